// Round 7
// baseline (245.822 us; speedup 1.0000x reference)
//
#include <hip/hip_runtime.h>
#include <math.h>

#define SEQ  1024
#define IND  256
#define CC   1024
#define NH   8
#define HD   128
#define BH   64      // BATCH*NH

typedef __bf16 bf16x8 __attribute__((ext_vector_type(8)));
typedef __bf16 bf16x4 __attribute__((ext_vector_type(4)));
typedef float  f32x4  __attribute__((ext_vector_type(4)));
typedef unsigned short u16;

static constexpr float RSDK = 0.08838834764831845f;  // 1/sqrt(128)

__device__ __forceinline__ u16 f2bf(float f) {
    unsigned int u = __float_as_uint(f);
    u += 0x7fffu + ((u >> 16) & 1u);   // round-to-nearest-even
    return (u16)(u >> 16);
}

__device__ __forceinline__ unsigned cvt_pk_bf16(float lo, float hi) {
    unsigned r;
    asm("v_cvt_pk_bf16_f32 %0, %1, %2" : "=v"(r) : "v"(lo), "v"(hi));
    return r;
}

// ---------------------------------------------------------------------------
// P0: fused prep. 1D grid 2944, block 256.
//   id <  2048          : x fp32 -> bf16 (4 elems/thread)
//   2048 <= id < 2816   : wq/wk/wv [256][1024] -> bf16 [1024][256] transpose
//   2816 <= id < 2944   : proj_w [1024][128]  -> bf16 [128][1024] transpose
// ---------------------------------------------------------------------------
__global__ __launch_bounds__(256) void prep_kernel(
    const float* __restrict__ x, u16* __restrict__ xb,
    const float* __restrict__ w0, const float* __restrict__ w1, const float* __restrict__ w2,
    u16* __restrict__ o0, u16* __restrict__ o1, u16* __restrict__ o2,
    const float* __restrict__ pw, u16* __restrict__ pT)
{
    __shared__ float tile[32][33];
    const int id = blockIdx.x;

    if (id < 2048) {
        const int i = id * 256 + threadIdx.x;
        float4 v = ((const float4*)x)[i];
        ushort4 o;
        o.x = f2bf(v.x); o.y = f2bf(v.y); o.z = f2bf(v.z); o.w = f2bf(v.w);
        ((ushort4*)xb)[i] = o;
        return;
    }

    const float* in; u16* out; int R, C, c0, r0;
    if (id < 2816) {
        const int rem = id - 2048;
        const int z = rem >> 8;              // 0..2
        const int rem2 = rem & 255;
        in  = (z == 0) ? w0 : (z == 1) ? w1 : w2;
        out = (z == 0) ? o0 : (z == 1) ? o1 : o2;
        R = IND; C = CC;
        c0 = (rem2 & 31) * 32;               // 0..992
        r0 = (rem2 >> 5) * 32;               // 0..224
    } else {
        const int rem = id - 2816;
        in = pw; out = pT;
        R = CC; C = HD;
        c0 = (rem & 3) * 32;                 // 0..96
        r0 = (rem >> 2) * 32;                // 0..992
    }

    const int row = threadIdx.x >> 3, col4 = (threadIdx.x & 7) * 4;
    float4 v = *(const float4*)&in[(size_t)(r0 + row) * C + c0 + col4];
    tile[row][col4 + 0] = v.x; tile[row][col4 + 1] = v.y;
    tile[row][col4 + 2] = v.z; tile[row][col4 + 3] = v.w;
    __syncthreads();
    ushort4 o;
    o.x = f2bf(tile[col4 + 0][row]);
    o.y = f2bf(tile[col4 + 1][row]);
    o.z = f2bf(tile[col4 + 2][row]);
    o.w = f2bf(tile[col4 + 3][row]);
    *(ushort4*)&out[(size_t)(c0 + row) * R + r0 + col4] = o;
}

// ---------------------------------------------------------------------------
// K1: QKV MFMA GEMM (R8/R12-exact). M=8192,N=1024,K=256. grid (64, 8, 3),
// block 256. 128x128 tile, BK=64, padded rows (stride 72 u16).
// mat 0/1 (Q,K): write [bh][n][128]; mat 2 (V): write TRANSPOSED [bh][128][n].
// ---------------------------------------------------------------------------
#define QKV_LDW 72
__global__ __launch_bounds__(256) void qkv_kernel(
    const u16* __restrict__ xb,
    const u16* __restrict__ wT0, const u16* __restrict__ wT1, const u16* __restrict__ wT2,
    const float* __restrict__ b0, const float* __restrict__ b1, const float* __restrict__ b2,
    u16* __restrict__ q_out, u16* __restrict__ k_out, u16* __restrict__ vt_out)
{
    const int mat = blockIdx.z;
    const u16* wT  = (mat == 0) ? wT0 : (mat == 1) ? wT1 : wT2;
    const float* wb = (mat == 0) ? b0 : (mat == 1) ? b1 : b2;
    const float scale = (mat == 0) ? RSDK : 1.0f;

    __shared__ __align__(16) u16 As[128 * QKV_LDW];
    __shared__ __align__(16) u16 Bs[128 * QKV_LDW];

    const int tid = threadIdx.x;
    const int lane = tid & 63, wave = tid >> 6;
    const int ln = lane & 15, quad = lane >> 4;
    const int m0 = blockIdx.x * 128;
    const int n0 = blockIdx.y * 128;
    const int wm = (wave & 1) * 64;
    const int wn = (wave >> 1) * 64;

    f32x4 acc[4][4];
    #pragma unroll
    for (int mb = 0; mb < 4; ++mb)
        #pragma unroll
        for (int nb = 0; nb < 4; ++nb)
            #pragma unroll
            for (int r = 0; r < 4; ++r) acc[mb][nb][r] = 0.0f;

    const int r8 = tid >> 3, pb8 = tid & 7;   // row-within-32, 16B block

    const u16* ag = xb + (size_t)(m0 + r8) * IND + pb8 * 8;
    const u16* bg = wT + (size_t)(n0 + r8) * IND + pb8 * 8;

    bf16x8 pa[4], pbv[4];
    #pragma unroll
    for (int c = 0; c < 4; ++c) {
        pa[c]  = *(const bf16x8*)(ag + (size_t)c * 32 * IND);
        pbv[c] = *(const bf16x8*)(bg + (size_t)c * 32 * IND);
    }

    for (int kt = 0; kt < 4; ++kt) {
        __syncthreads();
        #pragma unroll
        for (int c = 0; c < 4; ++c) {
            *(bf16x8*)(As + (size_t)(c * 32 + r8) * QKV_LDW + pb8 * 8) = pa[c];
            *(bf16x8*)(Bs + (size_t)(c * 32 + r8) * QKV_LDW + pb8 * 8) = pbv[c];
        }
        __syncthreads();
        if (kt < 3) {
            #pragma unroll
            for (int c = 0; c < 4; ++c) {
                pa[c]  = *(const bf16x8*)(ag + (size_t)c * 32 * IND + (kt + 1) * 64);
                pbv[c] = *(const bf16x8*)(bg + (size_t)c * 32 * IND + (kt + 1) * 64);
            }
        }
        #pragma unroll
        for (int ks = 0; ks < 2; ++ks) {
            bf16x8 af[4], bf[4];
            #pragma unroll
            for (int mb = 0; mb < 4; ++mb)
                af[mb] = *(const bf16x8*)(As + (size_t)(wm + mb * 16 + ln) * QKV_LDW
                                             + (ks * 4 + quad) * 8);
            #pragma unroll
            for (int nb = 0; nb < 4; ++nb)
                bf[nb] = *(const bf16x8*)(Bs + (size_t)(wn + nb * 16 + ln) * QKV_LDW
                                             + (ks * 4 + quad) * 8);
            #pragma unroll
            for (int mb = 0; mb < 4; ++mb)
                #pragma unroll
                for (int nb = 0; nb < 4; ++nb)
                    acc[mb][nb] = __builtin_amdgcn_mfma_f32_16x16x32_bf16(
                        af[mb], bf[nb], acc[mb][nb], 0, 0, 0);
        }
    }

    if (mat != 2) {
        u16* outp = (mat == 0) ? q_out : k_out;
        #pragma unroll
        for (int nb = 0; nb < 4; ++nb) {
            const int c = n0 + wn + nb * 16 + ln;
            const float bv = wb[c];
            const int h = c >> 7, d = c & 127;
            #pragma unroll
            for (int mb = 0; mb < 4; ++mb) {
                #pragma unroll
                for (int r = 0; r < 4; ++r) {
                    const int m = m0 + wm + mb * 16 + quad * 4 + r;
                    const int b = m >> 10, tok = m & 1023;
                    outp[((size_t)(b * NH + h) * SEQ + tok) * HD + d] =
                        f2bf((acc[mb][nb][r] + bv) * scale);
                }
            }
        }
    } else {
        // V: fused transpose -> Vt [bh][d][n]; 4 consecutive tokens per store
        #pragma unroll
        for (int nb = 0; nb < 4; ++nb) {
            const int c = n0 + wn + nb * 16 + ln;
            const float bv = wb[c];
            const int h = c >> 7, d = c & 127;
            #pragma unroll
            for (int mb = 0; mb < 4; ++mb) {
                const int m = m0 + wm + mb * 16 + quad * 4;
                const int b = m >> 10, tok0 = m & 1023;
                ushort4 o;
                o.x = f2bf(acc[mb][nb][0] + bv);
                o.y = f2bf(acc[mb][nb][1] + bv);
                o.z = f2bf(acc[mb][nb][2] + bv);
                o.w = f2bf(acc[mb][nb][3] + bv);
                *(ushort4*)&vt_out[((size_t)(b * NH + h) * HD + d) * SEQ + tok0] = o;
            }
        }
    }
}

// ---------------------------------------------------------------------------
// K2: flash attention, MFMA. R21: key-split within block for occupancy.
// Block 512 threads = 8 waves = 2 groups x 4 waves; group g processes
// k-tiles {2i+g}, i=0..15. Grid (64 bh, 8 q-blocks) -> 4096 waves =
// 4 waves/SIMD (was 2). Per-wave LDS work HALVES (16 tiles x 20 b128);
// total LDS instrs/CU unchanged -> LDS pipe (~61k cyc) becomes the floor.
// Rationale (R20 post-mortem): 2 waves/SIMD gave only ~24% issue occupancy;
// wall 138k cyc vs 61k LDS / 40k MFMA. Key-split adds waves WITHOUT adding
// per-wave LDS work (unlike R17's row-split). Unnormalized softmax makes the
// merge trivial: O and l are plain sums over keys -> group 1 writes fp32
// partials to LDS (stride-34 floats, 2-way-clean, aliases staging buffers,
// chunked by mb), group 0 adds + normalizes + stores. Benign fp reorder only.
// Same proven 2-barrier skeleton per iteration; groups have disjoint LDS
// slots (Ks[g]/Vs[g]); SQ_LDS_BANK_CONFLICT shown to be structural 2-way
// accounting (R17->R20 exactly proportional to instr count) — not a lever.
// Ks: [32 k][128 d] stride 136 u16; Vs: [128 d][32 k] stride 40 u16; x2.
// Negative results kept out: XOR swizzle (R3/4), P pair-pack via LDS (R7),
// V-direct (R9), bias-as-C (R13), exp2 fold (R14), single-barrier dbuf
// (R18 race), K-direct-global (R19 uncoalesced fragment reads).
// ---------------------------------------------------------------------------
#define KVB    32
#define KS_LDW 136
#define VS_LDW 40
#define KS_SZ  (KVB * KS_LDW)     // 4352 u16 per tile
#define VS_SZ  (128 * VS_LDW)     // 5120 u16 per tile
__global__ __launch_bounds__(512, 4) void attn_kernel(
    const u16* __restrict__ Q, const u16* __restrict__ K,
    const u16* __restrict__ Vt, const float* __restrict__ bias,
    u16* __restrict__ aout)
{
    __shared__ __align__(16) u16 SM[2 * KS_SZ + 2 * VS_SZ];   // 37888 B

    const int tid = threadIdx.x;
    const int lane = tid & 63, wave = tid >> 6;
    const int ln = lane & 15, quad = lane >> 4;
    const int g  = wave >> 2;          // key-half group (0: even tiles, 1: odd)
    const int wq = wave & 3;           // q-sub-tile within block
    const int bh = blockIdx.x;
    const int q0 = blockIdx.y * 128 + wq * 32;

    u16* Ksg = SM + g * KS_SZ;
    u16* Vsg = SM + 2 * KS_SZ + g * VS_SZ;

    bf16x8 qf[2][4];
    #pragma unroll
    for (int mb = 0; mb < 2; ++mb) {
        const u16* qp = Q + ((size_t)bh * SEQ + q0 + mb * 16 + ln) * HD + quad * 8;
        #pragma unroll
        for (int ks = 0; ks < 4; ++ks) qf[mb][ks] = *(const bf16x8*)(qp + ks * 32);
    }

    f32x4 Oa[2][8];
    #pragma unroll
    for (int mb = 0; mb < 2; ++mb)
        #pragma unroll
        for (int db = 0; db < 8; ++db)
            #pragma unroll
            for (int r = 0; r < 4; ++r) Oa[mb][db][r] = 0.0f;
    float l_loc[2] = {0.0f, 0.0f};   // partial l for query ln, per q-tile

    const u16* Kg0 = K  + (size_t)bh * SEQ * HD;
    const u16* Vg0 = Vt + (size_t)bh * HD * SEQ;
    const float* brow0 = bias + (size_t)(q0 + ln) * SEQ + quad * 4;
    const float* brow1 = brow0 + (size_t)16 * SEQ;

    // staging indices on the group-local 256 threads (R20-exact maps)
    const int st = tid & 255;
    const int r16 = st >> 4, pb16 = st & 15;   // K: 16 rows/pass
    const int r4  = st >> 2, pb4  = st & 3;    // V: 64 rows/pass

    const u16* kg = Kg0 + (size_t)r16 * HD + pb16 * 8;   // + tile*KVB*HD + c*16*HD
    const u16* vg = Vg0 + (size_t)r4 * SEQ + pb4 * 8;    // + c*64*SEQ + tile*KVB

    // prologue: load own group's first tile (tile g) into regs
    bf16x8 kp[2], vp[2];
    kp[0] = *(const bf16x8*)(kg + (size_t)g * KVB * HD);
    kp[1] = *(const bf16x8*)(kg + (size_t)g * KVB * HD + (size_t)16 * HD);
    vp[0] = *(const bf16x8*)(vg + g * KVB);
    vp[1] = *(const bf16x8*)(vg + (size_t)64 * SEQ + g * KVB);

    // bias prefetch for tile g: [mb][nb] = keys g*KVB + nb*16 + quad*4 + {0..3}
    float4 bpre[2][2];
    #pragma unroll
    for (int mb = 0; mb < 2; ++mb)
        #pragma unroll
        for (int nb = 0; nb < 2; ++nb)
            bpre[mb][nb] = *(const float4*)((mb ? brow1 : brow0) + g * KVB + nb * 16);

    for (int i = 0; i < 16; ++i) {
        __syncthreads();
        *(bf16x8*)(Ksg + (size_t)r16 * KS_LDW + pb16 * 8)        = kp[0];
        *(bf16x8*)(Ksg + (size_t)(16 + r16) * KS_LDW + pb16 * 8) = kp[1];
        *(bf16x8*)(Vsg + (size_t)r4 * VS_LDW + pb4 * 8)          = vp[0];
        *(bf16x8*)(Vsg + (size_t)(64 + r4) * VS_LDW + pb4 * 8)   = vp[1];
        __syncthreads();

        // prefetch own group's next tile (2(i+1)+g), off critical path
        if (i < 15) {
            const size_t t = (size_t)(2 * (i + 1) + g);
            kp[0] = *(const bf16x8*)(kg + t * KVB * HD);
            kp[1] = *(const bf16x8*)(kg + t * KVB * HD + (size_t)16 * HD);
            vp[0] = *(const bf16x8*)(vg + t * KVB);
            vp[1] = *(const bf16x8*)(vg + (size_t)64 * SEQ + t * KVB);
        }

        // ---- S^T = K Q^T (swapped); kf shared by both q-tiles ----
        float p8[2][2][4];
        #pragma unroll
        for (int nb = 0; nb < 2; ++nb) {
            const u16* kr = Ksg + (size_t)(nb * 16 + ln) * KS_LDW;
            bf16x8 kf[4];
            #pragma unroll
            for (int ks = 0; ks < 4; ++ks)
                kf[ks] = *(const bf16x8*)(kr + (ks * 4 + quad) * 8);
            #pragma unroll
            for (int mb = 0; mb < 2; ++mb) {
                f32x4 s;
                #pragma unroll
                for (int r = 0; r < 4; ++r) s[r] = 0.0f;
                #pragma unroll
                for (int ks = 0; ks < 4; ++ks)
                    s = __builtin_amdgcn_mfma_f32_16x16x32_bf16(kf[ks], qf[mb][ks], s, 0, 0, 0);
                #pragma unroll
                for (int r = 0; r < 4; ++r) {
                    const float p = __expf(s[r] + bpre[mb][nb][r]);
                    l_loc[mb] += p;
                    p8[mb][nb][r] = p;
                }
            }
        }

        // bias for next tile (after last use of bpre; hidden under PV)
        if (i < 15) {
            const int t = 2 * (i + 1) + g;
            #pragma unroll
            for (int mb = 0; mb < 2; ++mb)
                #pragma unroll
                for (int nb = 0; nb < 2; ++nb)
                    bpre[mb][nb] = *(const float4*)((mb ? brow1 : brow0)
                                                    + t * KVB + nb * 16);
        }

        // ---- P -> A fragments: pure-register 4-quad transpose, per tile ----
        bf16x8 af[2];
        #pragma unroll
        for (int mb = 0; mb < 2; ++mb) {
            unsigned x0 = cvt_pk_bf16(p8[mb][0][0], p8[mb][0][1]);
            unsigned x1 = cvt_pk_bf16(p8[mb][0][2], p8[mb][0][3]);
            unsigned y0 = cvt_pk_bf16(p8[mb][1][0], p8[mb][1][1]);
            unsigned y1 = cvt_pk_bf16(p8[mb][1][2], p8[mb][1][3]);
            asm("v_permlane32_swap_b32 %0, %1" : "+v"(x0), "+v"(y0));
            asm("v_permlane32_swap_b32 %0, %1" : "+v"(x1), "+v"(y1));
            asm("v_permlane16_swap_b32 %0, %1" : "+v"(x0), "+v"(y0));
            asm("v_permlane16_swap_b32 %0, %1" : "+v"(x1), "+v"(y1));
            union { unsigned u[4]; bf16x8 v; } afu;
            afu.u[0] = x0; afu.u[1] = x1; afu.u[2] = y0; afu.u[3] = y1;
            af[mb] = afu.v;   // P[q=ln][keys 8*quad .. 8*quad+7] of this tile
        }

        // ---- O += P V; vf shared by both q-tiles ----
        #pragma unroll
        for (int db = 0; db < 8; ++db) {
            bf16x8 vf = *(const bf16x8*)(Vsg + (size_t)(db * 16 + ln) * VS_LDW + quad * 8);
            #pragma unroll
            for (int mb = 0; mb < 2; ++mb)
                Oa[mb][db] = __builtin_amdgcn_mfma_f32_16x16x32_bf16(
                    af[mb], vf, Oa[mb][db], 0, 0, 0);
        }
    }

    // ---- merge group 1's partials into group 0 (chunked by mb) ----
    // M: [wq*64+lane][34] floats; 8704 floats = 34816 B <= 37888 (aliases SM).
    float* M = (float*)SM;
    #pragma unroll
    for (int mb = 0; mb < 2; ++mb) {
        __syncthreads();
        float* mp = M + (size_t)(wq * 64 + lane) * 34;
        if (g == 1) {
            #pragma unroll
            for (int db = 0; db < 8; ++db)
                #pragma unroll
                for (int r = 0; r < 4; ++r) mp[db * 4 + r] = Oa[mb][db][r];
            mp[32] = l_loc[mb];
        }
        __syncthreads();
        if (g == 0) {
            #pragma unroll
            for (int db = 0; db < 8; ++db)
                #pragma unroll
                for (int r = 0; r < 4; ++r) Oa[mb][db][r] += mp[db * 4 + r];
            l_loc[mb] += mp[32];
        }
    }

    if (g != 0) return;   // no barriers after this point

    // ---- l reduce across quads + epilogue, per q-tile (group 0 only) ----
    const int b = bh >> 3, h = bh & 7;
    #pragma unroll
    for (int mb = 0; mb < 2; ++mb) {
        float ltot = l_loc[mb];
        ltot += __shfl_xor(ltot, 16);
        ltot += __shfl_xor(ltot, 32);
        #pragma unroll
        for (int r = 0; r < 4; ++r) {
            const float inv = 1.0f / __shfl(ltot, quad * 4 + r);
            const int tok = q0 + mb * 16 + quad * 4 + r;
            u16* op = aout + ((size_t)(b * SEQ + tok)) * CC + h * HD + ln;
            #pragma unroll
            for (int db = 0; db < 8; ++db) op[db * 16] = f2bf(Oa[mb][db][r] * inv);
        }
    }
}

// ---------------------------------------------------------------------------
// K3: output projection, 4-way K-split (R12-exact). M=8192, N=128, K=1024.
// grid 512, block 256 (4 waves). Wave kh owns K-quarter of the SAME 16 rows;
// waves 1-3 write fp32 partials to LDS (stride 132), wave 0 sums + bias.
// (2048 waves = 8 waves/CU; this was the R12 win, total 229 -> 197.)
// ---------------------------------------------------------------------------
__global__ __launch_bounds__(256) void proj_kernel(
    const u16* __restrict__ A, const u16* __restrict__ pT,
    const float* __restrict__ pb, float* __restrict__ out)
{
    __shared__ float Rs[3][16 * 132];
    const int tid = threadIdx.x;
    const int lane = tid & 63, kh = tid >> 6;
    const int ln = lane & 15, quad = lane >> 4;
    const int m0 = blockIdx.x * 16;

    f32x4 acc[8];
    #pragma unroll
    for (int nb = 0; nb < 8; ++nb)
        #pragma unroll
        for (int r = 0; r < 4; ++r) acc[nb][r] = 0.0f;

    const u16* ap = A  + (size_t)(m0 + ln) * CC + kh * 256 + quad * 8;
    const u16* bp = pT + (size_t)ln * CC + kh * 256 + quad * 8;

    #pragma unroll
    for (int kt = 0; kt < 8; ++kt) {
        bf16x8 af = *(const bf16x8*)(ap + kt * 32);
        #pragma unroll
        for (int nb = 0; nb < 8; ++nb) {
            bf16x8 bf = *(const bf16x8*)(bp + (size_t)nb * 16 * CC + kt * 32);
            acc[nb] = __builtin_amdgcn_mfma_f32_16x16x32_bf16(af, bf, acc[nb], 0, 0, 0);
        }
    }

    if (kh > 0) {
        #pragma unroll
        for (int nb = 0; nb < 8; ++nb)
            #pragma unroll
            for (int r = 0; r < 4; ++r)
                Rs[kh - 1][(quad * 4 + r) * 132 + nb * 16 + ln] = acc[nb][r];
    }
    __syncthreads();
    if (kh == 0) {
        #pragma unroll
        for (int nb = 0; nb < 8; ++nb) {
            const int c = nb * 16 + ln;
            const float bv = pb[c];
            #pragma unroll
            for (int r = 0; r < 4; ++r) {
                const int ri = (quad * 4 + r) * 132 + c;
                out[(size_t)(m0 + quad * 4 + r) * HD + c] =
                    acc[nb][r] + Rs[0][ri] + Rs[1][ri] + Rs[2][ri] + bv;
            }
        }
    }
}

// ---------------------------------------------------------------------------
extern "C" void kernel_launch(void* const* d_in, const int* in_sizes, int n_in,
                              void* d_out, int out_size, void* d_ws, size_t ws_size,
                              hipStream_t stream)
{
    const float* x    = (const float*)d_in[0];
    const float* bias = (const float*)d_in[1];
    const float* wq   = (const float*)d_in[2];
    const float* wqb  = (const float*)d_in[3];
    const float* wk   = (const float*)d_in[4];
    const float* wkb  = (const float*)d_in[5];
    const float* wv   = (const float*)d_in[6];
    const float* wvb  = (const float*)d_in[7];
    const float* pw   = (const float*)d_in[8];
    const float* pb   = (const float*)d_in[9];
    float* out = (float*)d_out;

    u16* ws = (u16*)d_ws;
    size_t off = 0;
    u16* xb  = ws + off; off += (size_t)8192 * IND;     // 4 MB
    u16* wqT = ws + off; off += (size_t)CC * IND;       // 512 KB
    u16* wkT = ws + off; off += (size_t)CC * IND;
    u16* wvT = ws + off; off += (size_t)CC * IND;
    u16* pT  = ws + off; off += (size_t)HD * CC;        // 256 KB
    u16* Qw  = ws + off; off += (size_t)BH * SEQ * HD;  // 16 MB
    u16* Kw  = ws + off; off += (size_t)BH * SEQ * HD;
    u16* Vtw = ws + off; off += (size_t)BH * HD * SEQ;
    u16* Aw  = ws + off; off += (size_t)8192 * CC;      // 16 MB

    prep_kernel<<<2944, 256, 0, stream>>>(x, xb, wq, wk, wv, wqT, wkT, wvT, pw, pT);
    qkv_kernel<<<dim3(64, 8, 3), 256, 0, stream>>>(
        xb, wqT, wkT, wvT, wqb, wkb, wvb, Qw, Kw, Vtw);
    attn_kernel<<<dim3(64, 8), 512, 0, stream>>>(Qw, Kw, Vtw, bias, Aw);
    proj_kernel<<<512, 256, 0, stream>>>(Aw, pT, pb, out);
}

// Round 8
// 179.684 us; speedup vs baseline: 1.3681x; 1.3681x over previous
//
#include <hip/hip_runtime.h>
#include <math.h>

#define SEQ  1024
#define IND  256
#define CC   1024
#define NH   8
#define HD   128
#define BH   64      // BATCH*NH

typedef __bf16 bf16x8 __attribute__((ext_vector_type(8)));
typedef __bf16 bf16x4 __attribute__((ext_vector_type(4)));
typedef float  f32x4  __attribute__((ext_vector_type(4)));
typedef unsigned short u16;

static constexpr float RSDK = 0.08838834764831845f;  // 1/sqrt(128)

__device__ __forceinline__ u16 f2bf(float f) {
    unsigned int u = __float_as_uint(f);
    u += 0x7fffu + ((u >> 16) & 1u);   // round-to-nearest-even
    return (u16)(u >> 16);
}

__device__ __forceinline__ unsigned cvt_pk_bf16(float lo, float hi) {
    unsigned r;
    asm("v_cvt_pk_bf16_f32 %0, %1, %2" : "=v"(r) : "v"(lo), "v"(hi));
    return r;
}

// global -> LDS direct (16B/lane). LDS dest is WAVE-UNIFORM base; lane l
// deposits at base + l*16B. Global src is per-lane.
__device__ __forceinline__ void gload16(const u16* g, u16* l) {
    __builtin_amdgcn_global_load_lds(
        (const __attribute__((address_space(1))) unsigned int*)g,
        (__attribute__((address_space(3))) unsigned int*)l, 16, 0, 0);
}

// ---------------------------------------------------------------------------
// P0: fused prep. 1D grid 2944, block 256.
//   id <  2048          : x fp32 -> bf16 (4 elems/thread)
//   2048 <= id < 2816   : wq/wk/wv [256][1024] -> bf16 [1024][256] transpose
//   2816 <= id < 2944   : proj_w [1024][128]  -> bf16 [128][1024] transpose
// ---------------------------------------------------------------------------
__global__ __launch_bounds__(256) void prep_kernel(
    const float* __restrict__ x, u16* __restrict__ xb,
    const float* __restrict__ w0, const float* __restrict__ w1, const float* __restrict__ w2,
    u16* __restrict__ o0, u16* __restrict__ o1, u16* __restrict__ o2,
    const float* __restrict__ pw, u16* __restrict__ pT)
{
    __shared__ float tile[32][33];
    const int id = blockIdx.x;

    if (id < 2048) {
        const int i = id * 256 + threadIdx.x;
        float4 v = ((const float4*)x)[i];
        ushort4 o;
        o.x = f2bf(v.x); o.y = f2bf(v.y); o.z = f2bf(v.z); o.w = f2bf(v.w);
        ((ushort4*)xb)[i] = o;
        return;
    }

    const float* in; u16* out; int R, C, c0, r0;
    if (id < 2816) {
        const int rem = id - 2048;
        const int z = rem >> 8;              // 0..2
        const int rem2 = rem & 255;
        in  = (z == 0) ? w0 : (z == 1) ? w1 : w2;
        out = (z == 0) ? o0 : (z == 1) ? o1 : o2;
        R = IND; C = CC;
        c0 = (rem2 & 31) * 32;               // 0..992
        r0 = (rem2 >> 5) * 32;               // 0..224
    } else {
        const int rem = id - 2816;
        in = pw; out = pT;
        R = CC; C = HD;
        c0 = (rem & 3) * 32;                 // 0..96
        r0 = (rem >> 2) * 32;                // 0..992
    }

    const int row = threadIdx.x >> 3, col4 = (threadIdx.x & 7) * 4;
    float4 v = *(const float4*)&in[(size_t)(r0 + row) * C + c0 + col4];
    tile[row][col4 + 0] = v.x; tile[row][col4 + 1] = v.y;
    tile[row][col4 + 2] = v.z; tile[row][col4 + 3] = v.w;
    __syncthreads();
    ushort4 o;
    o.x = f2bf(tile[col4 + 0][row]);
    o.y = f2bf(tile[col4 + 1][row]);
    o.z = f2bf(tile[col4 + 2][row]);
    o.w = f2bf(tile[col4 + 3][row]);
    *(ushort4*)&out[(size_t)(c0 + row) * R + r0 + col4] = o;
}

// ---------------------------------------------------------------------------
// K1: QKV MFMA GEMM — R22 rewrite in the m97 structure. M=8192,N=1024,K=256.
// grid (64, 8, 3), block 256, 128x128 tile, BK=64, 4 kt iterations.
// Changes vs R8/R12 (values bit-exact: same kt/ks accumulation order):
//  (1) staging via global_load_lds width=16 into LINEAR As/Bs [128][64]
//      (no reg round-trip; compiler never auto-emits this). Accepts the
//      known 16-way fragment-read conflict of linear LDS (T2 swizzle is
//      regime-gated NULL on 2-phase schedules — not attempted).
//  (2) Q/K use SWAPPED operands mfma(bf, af) -> lane holds 4 consecutive d
//      (acc[mb][nb][r] = C[m=mb*16+ln][d0=wn+nb*16+quad*4 + r]) -> epilogue
//      is 16 ushort4 stores/lane instead of 64 scalar 2B stores.
//      V keeps unswapped order + its transposed ushort4 path.
// n-tile = one head: h = blockIdx.y, d = wn+nb*16+... (n0 multiple of 128).
// ---------------------------------------------------------------------------
__global__ __launch_bounds__(256) void qkv_kernel(
    const u16* __restrict__ xb,
    const u16* __restrict__ wT0, const u16* __restrict__ wT1, const u16* __restrict__ wT2,
    const float* __restrict__ b0, const float* __restrict__ b1, const float* __restrict__ b2,
    u16* __restrict__ q_out, u16* __restrict__ k_out, u16* __restrict__ vt_out)
{
    const int mat = blockIdx.z;
    const u16* wT  = (mat == 0) ? wT0 : (mat == 1) ? wT1 : wT2;
    const float* wb = (mat == 0) ? b0 : (mat == 1) ? b1 : b2;
    const float scale = (mat == 0) ? RSDK : 1.0f;

    __shared__ __align__(16) u16 As[128 * 64];   // 16 KB, linear
    __shared__ __align__(16) u16 Bs[128 * 64];   // 16 KB, linear

    const int tid = threadIdx.x;
    const int lane = tid & 63, wave = tid >> 6;
    const int ln = lane & 15, quad = lane >> 4;
    const int m0 = blockIdx.x * 128;
    const int n0 = blockIdx.y * 128;
    const int wm = (wave & 1) * 64;
    const int wn = (wave >> 1) * 64;

    f32x4 acc[4][4];
    #pragma unroll
    for (int mb = 0; mb < 4; ++mb)
        #pragma unroll
        for (int nb = 0; nb < 4; ++nb)
            #pragma unroll
            for (int r = 0; r < 4; ++r) acc[mb][nb][r] = 0.0f;

    // gload_lds map: chunk c covers rows (wave*4+c)*8 .. +7; lane l ->
    // row +l/8, col (l&7)*8 u16 (8 lanes = one 128B row segment, coalesced).
    const int grow = lane >> 3;           // 0..7
    const int gcol = (lane & 7) * 8;      // u16 units

    for (int kt = 0; kt < 4; ++kt) {
        __syncthreads();   // previous tile's compute done before overwrite
        #pragma unroll
        for (int c = 0; c < 4; ++c) {
            const int rb = (wave * 4 + c) * 8;
            gload16(xb + (size_t)(m0 + rb + grow) * IND + kt * 64 + gcol,
                    As + (size_t)(wave * 4 + c) * 512);
            gload16(wT + (size_t)(n0 + rb + grow) * IND + kt * 64 + gcol,
                    Bs + (size_t)(wave * 4 + c) * 512);
        }
        __syncthreads();   // vmcnt(0) drained by compiler before barrier

        #pragma unroll
        for (int ks = 0; ks < 2; ++ks) {
            bf16x8 af[4], bf[4];
            #pragma unroll
            for (int mb = 0; mb < 4; ++mb)
                af[mb] = *(const bf16x8*)(As + (size_t)(wm + mb * 16 + ln) * 64
                                             + (ks * 4 + quad) * 8);
            #pragma unroll
            for (int nb = 0; nb < 4; ++nb)
                bf[nb] = *(const bf16x8*)(Bs + (size_t)(wn + nb * 16 + ln) * 64
                                             + (ks * 4 + quad) * 8);
            if (mat != 2) {
                // swapped: acc[mb][nb][r] = C[m = mb*16+ln][n = nb*16+quad*4+r]
                #pragma unroll
                for (int mb = 0; mb < 4; ++mb)
                    #pragma unroll
                    for (int nb = 0; nb < 4; ++nb)
                        acc[mb][nb] = __builtin_amdgcn_mfma_f32_16x16x32_bf16(
                            bf[nb], af[mb], acc[mb][nb], 0, 0, 0);
            } else {
                // unswapped: acc[mb][nb][r] = C[m = mb*16+quad*4+r][n = nb*16+ln]
                #pragma unroll
                for (int mb = 0; mb < 4; ++mb)
                    #pragma unroll
                    for (int nb = 0; nb < 4; ++nb)
                        acc[mb][nb] = __builtin_amdgcn_mfma_f32_16x16x32_bf16(
                            af[mb], bf[nb], acc[mb][nb], 0, 0, 0);
            }
        }
    }

    if (mat != 2) {
        u16* outp = (mat == 0) ? q_out : k_out;
        const int h = n0 >> 7;   // one head per n-tile
        float4 bv[4];
        #pragma unroll
        for (int nb = 0; nb < 4; ++nb)
            bv[nb] = *(const float4*)&wb[n0 + wn + nb * 16 + quad * 4];
        #pragma unroll
        for (int mb = 0; mb < 4; ++mb) {
            const int m = m0 + wm + mb * 16 + ln;
            const int b = m >> 10, tok = m & 1023;
            u16* orow = outp + ((size_t)(b * NH + h) * SEQ + tok) * HD;
            #pragma unroll
            for (int nb = 0; nb < 4; ++nb) {
                const int d0 = wn + nb * 16 + quad * 4;
                ushort4 o;
                o.x = f2bf((acc[mb][nb][0] + bv[nb].x) * scale);
                o.y = f2bf((acc[mb][nb][1] + bv[nb].y) * scale);
                o.z = f2bf((acc[mb][nb][2] + bv[nb].z) * scale);
                o.w = f2bf((acc[mb][nb][3] + bv[nb].w) * scale);
                *(ushort4*)&orow[d0] = o;
            }
        }
    } else {
        // V: fused transpose -> Vt [bh][d][n]; 4 consecutive tokens per store
        #pragma unroll
        for (int nb = 0; nb < 4; ++nb) {
            const int c = n0 + wn + nb * 16 + ln;
            const float bv = wb[c];
            const int h = c >> 7, d = c & 127;
            #pragma unroll
            for (int mb = 0; mb < 4; ++mb) {
                const int m = m0 + wm + mb * 16 + quad * 4;
                const int b = m >> 10, tok0 = m & 1023;
                ushort4 o;
                o.x = f2bf(acc[mb][nb][0] + bv);
                o.y = f2bf(acc[mb][nb][1] + bv);
                o.z = f2bf(acc[mb][nb][2] + bv);
                o.w = f2bf(acc[mb][nb][3] + bv);
                *(ushort4*)&vt_out[((size_t)(b * NH + h) * HD + d) * SEQ + tok0] = o;
            }
        }
    }
}

// ---------------------------------------------------------------------------
// K2: flash attention, MFMA. R20-EXACT (best measured: attn 57.5 us,
// total 172.1). Wave owns 32 q-rows (2 q-tiles) sharing one set of K/V
// fragment reads. grid (64 bh, 8 q-blocks), block 256, launch_bounds(256,2).
// Closed frontiers (do not revisit): R18 single-barrier dbuf (RACE);
// R19 K-direct-from-global (uncoalesced fragment reads, 69->163 us);
// R21 key-split 512-thread block (launch_bounds(512,4) caps VGPR at 128 ->
// accumulator SPILL, FETCH+WRITE +250MB, 57->127 us — 2-q-tile waves need
// ~150-200 regs, so max 2 waves/SIMD; R20 is the optimum of this family).
// SQ_LDS_BANK_CONFLICT is structural 2-way accounting (R17->R20 exactly
// proportional to instr count) — not a lever.
// Unnormalized softmax (|s| <~ 10 << 88), p = exp(s), l in regs,
// in-register P via swapped QK^T + cvt_pk/permlane 4-quad transpose.
// Ks: [32 k][128 d] stride 136 u16; Vs: [128 d][32 k] stride 40 u16.
// Other negatives kept out: XOR swizzle (R3/4), P pair-pack via LDS (R7),
// V-direct (R9), bias-as-C (R13), exp2 fold (R14).
// ---------------------------------------------------------------------------
#define KVB    32
#define KS_LDW 136
#define VS_LDW 40
__global__ __launch_bounds__(256, 2) void attn_kernel(
    const u16* __restrict__ Q, const u16* __restrict__ K,
    const u16* __restrict__ Vt, const float* __restrict__ bias,
    u16* __restrict__ aout)
{
    __shared__ __align__(16) u16 Ks[KVB * KS_LDW];        // 8704 B
    __shared__ __align__(16) u16 Vs[128 * VS_LDW];        // 10240 B

    const int tid = threadIdx.x;
    const int lane = tid & 63, wave = tid >> 6;
    const int ln = lane & 15, quad = lane >> 4;
    const int bh = blockIdx.x;
    const int q0 = blockIdx.y * 128 + wave * 32;

    bf16x8 qf[2][4];
    #pragma unroll
    for (int mb = 0; mb < 2; ++mb) {
        const u16* qp = Q + ((size_t)bh * SEQ + q0 + mb * 16 + ln) * HD + quad * 8;
        #pragma unroll
        for (int ks = 0; ks < 4; ++ks) qf[mb][ks] = *(const bf16x8*)(qp + ks * 32);
    }

    f32x4 Oa[2][8];
    #pragma unroll
    for (int mb = 0; mb < 2; ++mb)
        #pragma unroll
        for (int db = 0; db < 8; ++db)
            #pragma unroll
            for (int r = 0; r < 4; ++r) Oa[mb][db][r] = 0.0f;
    float l_loc[2] = {0.0f, 0.0f};   // partial l for query ln, per q-tile

    const u16* Kg0 = K  + (size_t)bh * SEQ * HD;
    const u16* Vg0 = Vt + (size_t)bh * HD * SEQ;
    // bias rows for THIS lane's queries (ln per tile); float4 in key dim
    const float* brow0 = bias + (size_t)(q0 + ln) * SEQ + quad * 4;
    const float* brow1 = brow0 + (size_t)16 * SEQ;

    // staging indices (R17-exact)
    const int r16 = tid >> 4, pb16 = tid & 15;   // K: 16 rows/pass
    const int r4  = tid >> 2, pb4  = tid & 3;    // V: 64 rows/pass

    const u16* kg = Kg0 + (size_t)r16 * HD + pb16 * 8;   // + kt*KVB*HD + c*16*HD
    const u16* vg = Vg0 + (size_t)r4 * SEQ + pb4 * 8;    // + c*64*SEQ + kt*KVB

    bf16x8 kp[2], vp[2];
    #pragma unroll
    for (int c = 0; c < 2; ++c) {
        kp[c] = *(const bf16x8*)(kg + (size_t)c * 16 * HD);
        vp[c] = *(const bf16x8*)(vg + (size_t)c * 64 * SEQ);
    }

    // bias prefetch for kt=0: [mb][nb] = keys nb*16 + quad*4 + {0..3}
    float4 bpre[2][2];
    #pragma unroll
    for (int mb = 0; mb < 2; ++mb)
        #pragma unroll
        for (int nb = 0; nb < 2; ++nb)
            bpre[mb][nb] = *(const float4*)((mb ? brow1 : brow0) + nb * 16);

    for (int kt = 0; kt < 32; ++kt) {
        __syncthreads();
        #pragma unroll
        for (int c = 0; c < 2; ++c) {
            *(bf16x8*)(Ks + (size_t)(c * 16 + r16) * KS_LDW + pb16 * 8) = kp[c];
            *(bf16x8*)(Vs + (size_t)(c * 64 + r4) * VS_LDW + pb4 * 8)   = vp[c];
        }
        __syncthreads();

        // prefetch next K/V tile (off critical path)
        if (kt < 31) {
            #pragma unroll
            for (int c = 0; c < 2; ++c) {
                kp[c] = *(const bf16x8*)(kg + (size_t)(kt + 1) * KVB * HD + (size_t)c * 16 * HD);
                vp[c] = *(const bf16x8*)(vg + (size_t)c * 64 * SEQ + (kt + 1) * KVB);
            }
        }

        // ---- S^T = K Q^T (swapped); kf shared by both q-tiles ----
        float p8[2][2][4];
        #pragma unroll
        for (int nb = 0; nb < 2; ++nb) {
            const u16* kr = Ks + (size_t)(nb * 16 + ln) * KS_LDW;
            bf16x8 kf[4];
            #pragma unroll
            for (int ks = 0; ks < 4; ++ks)
                kf[ks] = *(const bf16x8*)(kr + (ks * 4 + quad) * 8);
            #pragma unroll
            for (int mb = 0; mb < 2; ++mb) {
                f32x4 s;
                #pragma unroll
                for (int r = 0; r < 4; ++r) s[r] = 0.0f;
                #pragma unroll
                for (int ks = 0; ks < 4; ++ks)
                    s = __builtin_amdgcn_mfma_f32_16x16x32_bf16(kf[ks], qf[mb][ks], s, 0, 0, 0);
                #pragma unroll
                for (int r = 0; r < 4; ++r) {
                    const float p = __expf(s[r] + bpre[mb][nb][r]);
                    l_loc[mb] += p;
                    p8[mb][nb][r] = p;
                }
            }
        }

        // bias for kt+1 (after last use of bpre; hidden under PV)
        if (kt < 31) {
            #pragma unroll
            for (int mb = 0; mb < 2; ++mb)
                #pragma unroll
                for (int nb = 0; nb < 2; ++nb)
                    bpre[mb][nb] = *(const float4*)((mb ? brow1 : brow0)
                                                    + (kt + 1) * KVB + nb * 16);
        }

        // ---- P -> A fragments: pure-register 4-quad transpose, per tile ----
        bf16x8 af[2];
        #pragma unroll
        for (int mb = 0; mb < 2; ++mb) {
            unsigned x0 = cvt_pk_bf16(p8[mb][0][0], p8[mb][0][1]);
            unsigned x1 = cvt_pk_bf16(p8[mb][0][2], p8[mb][0][3]);
            unsigned y0 = cvt_pk_bf16(p8[mb][1][0], p8[mb][1][1]);
            unsigned y1 = cvt_pk_bf16(p8[mb][1][2], p8[mb][1][3]);
            asm("v_permlane32_swap_b32 %0, %1" : "+v"(x0), "+v"(y0));
            asm("v_permlane32_swap_b32 %0, %1" : "+v"(x1), "+v"(y1));
            asm("v_permlane16_swap_b32 %0, %1" : "+v"(x0), "+v"(y0));
            asm("v_permlane16_swap_b32 %0, %1" : "+v"(x1), "+v"(y1));
            union { unsigned u[4]; bf16x8 v; } afu;
            afu.u[0] = x0; afu.u[1] = x1; afu.u[2] = y0; afu.u[3] = y1;
            af[mb] = afu.v;   // P[q=ln][keys 8*quad .. 8*quad+7]
        }

        // ---- O += P V; vf shared by both q-tiles ----
        #pragma unroll
        for (int db = 0; db < 8; ++db) {
            bf16x8 vf = *(const bf16x8*)(Vs + (size_t)(db * 16 + ln) * VS_LDW + quad * 8);
            #pragma unroll
            for (int mb = 0; mb < 2; ++mb)
                Oa[mb][db] = __builtin_amdgcn_mfma_f32_16x16x32_bf16(
                    af[mb], vf, Oa[mb][db], 0, 0, 0);
        }
    }

    // ---- l reduce across quads + epilogue, per q-tile ----
    const int b = bh >> 3, h = bh & 7;
    #pragma unroll
    for (int mb = 0; mb < 2; ++mb) {
        float ltot = l_loc[mb];
        ltot += __shfl_xor(ltot, 16);
        ltot += __shfl_xor(ltot, 32);
        #pragma unroll
        for (int r = 0; r < 4; ++r) {
            const float inv = 1.0f / __shfl(ltot, quad * 4 + r);
            const int tok = q0 + mb * 16 + quad * 4 + r;
            u16* op = aout + ((size_t)(b * SEQ + tok)) * CC + h * HD + ln;
            #pragma unroll
            for (int db = 0; db < 8; ++db) op[db * 16] = f2bf(Oa[mb][db][r] * inv);
        }
    }
}

// ---------------------------------------------------------------------------
// K3: output projection, 4-way K-split (R12-exact). M=8192, N=128, K=1024.
// grid 512, block 256 (4 waves). Wave kh owns K-quarter of the SAME 16 rows;
// waves 1-3 write fp32 partials to LDS (stride 132), wave 0 sums + bias.
// (2048 waves = 8 waves/CU; this was the R12 win, total 229 -> 197.)
// ---------------------------------------------------------------------------
__global__ __launch_bounds__(256) void proj_kernel(
    const u16* __restrict__ A, const u16* __restrict__ pT,
    const float* __restrict__ pb, float* __restrict__ out)
{
    __shared__ float Rs[3][16 * 132];
    const int tid = threadIdx.x;
    const int lane = tid & 63, kh = tid >> 6;
    const int ln = lane & 15, quad = lane >> 4;
    const int m0 = blockIdx.x * 16;

    f32x4 acc[8];
    #pragma unroll
    for (int nb = 0; nb < 8; ++nb)
        #pragma unroll
        for (int r = 0; r < 4; ++r) acc[nb][r] = 0.0f;

    const u16* ap = A  + (size_t)(m0 + ln) * CC + kh * 256 + quad * 8;
    const u16* bp = pT + (size_t)ln * CC + kh * 256 + quad * 8;

    #pragma unroll
    for (int kt = 0; kt < 8; ++kt) {
        bf16x8 af = *(const bf16x8*)(ap + kt * 32);
        #pragma unroll
        for (int nb = 0; nb < 8; ++nb) {
            bf16x8 bf = *(const bf16x8*)(bp + (size_t)nb * 16 * CC + kt * 32);
            acc[nb] = __builtin_amdgcn_mfma_f32_16x16x32_bf16(af, bf, acc[nb], 0, 0, 0);
        }
    }

    if (kh > 0) {
        #pragma unroll
        for (int nb = 0; nb < 8; ++nb)
            #pragma unroll
            for (int r = 0; r < 4; ++r)
                Rs[kh - 1][(quad * 4 + r) * 132 + nb * 16 + ln] = acc[nb][r];
    }
    __syncthreads();
    if (kh == 0) {
        #pragma unroll
        for (int nb = 0; nb < 8; ++nb) {
            const int c = nb * 16 + ln;
            const float bv = pb[c];
            #pragma unroll
            for (int r = 0; r < 4; ++r) {
                const int ri = (quad * 4 + r) * 132 + c;
                out[(size_t)(m0 + quad * 4 + r) * HD + c] =
                    acc[nb][r] + Rs[0][ri] + Rs[1][ri] + Rs[2][ri] + bv;
            }
        }
    }
}

// ---------------------------------------------------------------------------
extern "C" void kernel_launch(void* const* d_in, const int* in_sizes, int n_in,
                              void* d_out, int out_size, void* d_ws, size_t ws_size,
                              hipStream_t stream)
{
    const float* x    = (const float*)d_in[0];
    const float* bias = (const float*)d_in[1];
    const float* wq   = (const float*)d_in[2];
    const float* wqb  = (const float*)d_in[3];
    const float* wk   = (const float*)d_in[4];
    const float* wkb  = (const float*)d_in[5];
    const float* wv   = (const float*)d_in[6];
    const float* wvb  = (const float*)d_in[7];
    const float* pw   = (const float*)d_in[8];
    const float* pb   = (const float*)d_in[9];
    float* out = (float*)d_out;

    u16* ws = (u16*)d_ws;
    size_t off = 0;
    u16* xb  = ws + off; off += (size_t)8192 * IND;     // 4 MB
    u16* wqT = ws + off; off += (size_t)CC * IND;       // 512 KB
    u16* wkT = ws + off; off += (size_t)CC * IND;
    u16* wvT = ws + off; off += (size_t)CC * IND;
    u16* pT  = ws + off; off += (size_t)HD * CC;        // 256 KB
    u16* Qw  = ws + off; off += (size_t)BH * SEQ * HD;  // 16 MB
    u16* Kw  = ws + off; off += (size_t)BH * SEQ * HD;
    u16* Vtw = ws + off; off += (size_t)BH * HD * SEQ;
    u16* Aw  = ws + off; off += (size_t)8192 * CC;      // 16 MB

    prep_kernel<<<2944, 256, 0, stream>>>(x, xb, wq, wk, wv, wqT, wkT, wvT, pw, pT);
    qkv_kernel<<<dim3(64, 8, 3), 256, 0, stream>>>(
        xb, wqT, wkT, wvT, wqb, wkb, wvb, Qw, Kw, Vtw);
    attn_kernel<<<dim3(64, 8), 256, 0, stream>>>(Qw, Kw, Vtw, bias, Aw);
    proj_kernel<<<512, 256, 0, stream>>>(Aw, pT, pb, out);
}

// Round 9
// 179.276 us; speedup vs baseline: 1.3712x; 1.0023x over previous
//
#include <hip/hip_runtime.h>
#include <math.h>

#define SEQ  1024
#define IND  256
#define CC   1024
#define NH   8
#define HD   128
#define BH   64      // BATCH*NH

typedef __bf16 bf16x8 __attribute__((ext_vector_type(8)));
typedef __bf16 bf16x4 __attribute__((ext_vector_type(4)));
typedef float  f32x4  __attribute__((ext_vector_type(4)));
typedef unsigned short u16;

static constexpr float RSDK = 0.08838834764831845f;  // 1/sqrt(128)

__device__ __forceinline__ u16 f2bf(float f) {
    unsigned int u = __float_as_uint(f);
    u += 0x7fffu + ((u >> 16) & 1u);   // round-to-nearest-even
    return (u16)(u >> 16);
}

__device__ __forceinline__ unsigned cvt_pk_bf16(float lo, float hi) {
    unsigned r;
    asm("v_cvt_pk_bf16_f32 %0, %1, %2" : "=v"(r) : "v"(lo), "v"(hi));
    return r;
}

// ---------------------------------------------------------------------------
// P0: fused prep. 1D grid 2944, block 256.
//   id <  2048          : x fp32 -> bf16 (4 elems/thread)
//   2048 <= id < 2816   : wq/wk/wv [256][1024] -> bf16 [1024][256] transpose
//   2816 <= id < 2944   : proj_w [1024][128]  -> bf16 [128][1024] transpose
// ---------------------------------------------------------------------------
__global__ __launch_bounds__(256) void prep_kernel(
    const float* __restrict__ x, u16* __restrict__ xb,
    const float* __restrict__ w0, const float* __restrict__ w1, const float* __restrict__ w2,
    u16* __restrict__ o0, u16* __restrict__ o1, u16* __restrict__ o2,
    const float* __restrict__ pw, u16* __restrict__ pT)
{
    __shared__ float tile[32][33];
    const int id = blockIdx.x;

    if (id < 2048) {
        const int i = id * 256 + threadIdx.x;
        float4 v = ((const float4*)x)[i];
        ushort4 o;
        o.x = f2bf(v.x); o.y = f2bf(v.y); o.z = f2bf(v.z); o.w = f2bf(v.w);
        ((ushort4*)xb)[i] = o;
        return;
    }

    const float* in; u16* out; int R, C, c0, r0;
    if (id < 2816) {
        const int rem = id - 2048;
        const int z = rem >> 8;              // 0..2
        const int rem2 = rem & 255;
        in  = (z == 0) ? w0 : (z == 1) ? w1 : w2;
        out = (z == 0) ? o0 : (z == 1) ? o1 : o2;
        R = IND; C = CC;
        c0 = (rem2 & 31) * 32;               // 0..992
        r0 = (rem2 >> 5) * 32;               // 0..224
    } else {
        const int rem = id - 2816;
        in = pw; out = pT;
        R = CC; C = HD;
        c0 = (rem & 3) * 32;                 // 0..96
        r0 = (rem >> 2) * 32;                // 0..992
    }

    const int row = threadIdx.x >> 3, col4 = (threadIdx.x & 7) * 4;
    float4 v = *(const float4*)&in[(size_t)(r0 + row) * C + c0 + col4];
    tile[row][col4 + 0] = v.x; tile[row][col4 + 1] = v.y;
    tile[row][col4 + 2] = v.z; tile[row][col4 + 3] = v.w;
    __syncthreads();
    ushort4 o;
    o.x = f2bf(tile[col4 + 0][row]);
    o.y = f2bf(tile[col4 + 1][row]);
    o.z = f2bf(tile[col4 + 2][row]);
    o.w = f2bf(tile[col4 + 3][row]);
    *(ushort4*)&out[(size_t)(c0 + row) * R + r0 + col4] = o;
}

// ---------------------------------------------------------------------------
// K1: QKV MFMA GEMM — R23 hybrid. M=8192,N=1024,K=256. grid (64, 8, 3),
// block 256. 128x128 tile, BK=64, PADDED rows (stride 72 u16) reg-staged
// (R12-proven; R22's gload_lds+linear-LDS was a wash: 2-phase regime hides
// staging wins, linear LDS added 16-way read conflicts). KEPT from R22:
// Q/K use SWAPPED operands mfma(bf, af) -> lane holds 4 consecutive d ->
// epilogue is 16 ushort4 stores/lane instead of 64 scalar 2B stores
// (bit-exact; R22 confirmed absmax unchanged). V unswapped + transposed
// ushort4 path. h = blockIdx.y (one head per n-tile).
// ---------------------------------------------------------------------------
#define QKV_LDW 72
__global__ __launch_bounds__(256) void qkv_kernel(
    const u16* __restrict__ xb,
    const u16* __restrict__ wT0, const u16* __restrict__ wT1, const u16* __restrict__ wT2,
    const float* __restrict__ b0, const float* __restrict__ b1, const float* __restrict__ b2,
    u16* __restrict__ q_out, u16* __restrict__ k_out, u16* __restrict__ vt_out)
{
    const int mat = blockIdx.z;
    const u16* wT  = (mat == 0) ? wT0 : (mat == 1) ? wT1 : wT2;
    const float* wb = (mat == 0) ? b0 : (mat == 1) ? b1 : b2;
    const float scale = (mat == 0) ? RSDK : 1.0f;

    __shared__ __align__(16) u16 As[128 * QKV_LDW];
    __shared__ __align__(16) u16 Bs[128 * QKV_LDW];

    const int tid = threadIdx.x;
    const int lane = tid & 63, wave = tid >> 6;
    const int ln = lane & 15, quad = lane >> 4;
    const int m0 = blockIdx.x * 128;
    const int n0 = blockIdx.y * 128;
    const int wm = (wave & 1) * 64;
    const int wn = (wave >> 1) * 64;

    f32x4 acc[4][4];
    #pragma unroll
    for (int mb = 0; mb < 4; ++mb)
        #pragma unroll
        for (int nb = 0; nb < 4; ++nb)
            #pragma unroll
            for (int r = 0; r < 4; ++r) acc[mb][nb][r] = 0.0f;

    const int r8 = tid >> 3, pb8 = tid & 7;   // row-within-32, 16B block

    const u16* ag = xb + (size_t)(m0 + r8) * IND + pb8 * 8;
    const u16* bg = wT + (size_t)(n0 + r8) * IND + pb8 * 8;

    bf16x8 pa[4], pbv[4];
    #pragma unroll
    for (int c = 0; c < 4; ++c) {
        pa[c]  = *(const bf16x8*)(ag + (size_t)c * 32 * IND);
        pbv[c] = *(const bf16x8*)(bg + (size_t)c * 32 * IND);
    }

    for (int kt = 0; kt < 4; ++kt) {
        __syncthreads();
        #pragma unroll
        for (int c = 0; c < 4; ++c) {
            *(bf16x8*)(As + (size_t)(c * 32 + r8) * QKV_LDW + pb8 * 8) = pa[c];
            *(bf16x8*)(Bs + (size_t)(c * 32 + r8) * QKV_LDW + pb8 * 8) = pbv[c];
        }
        __syncthreads();
        if (kt < 3) {
            #pragma unroll
            for (int c = 0; c < 4; ++c) {
                pa[c]  = *(const bf16x8*)(ag + (size_t)c * 32 * IND + (kt + 1) * 64);
                pbv[c] = *(const bf16x8*)(bg + (size_t)c * 32 * IND + (kt + 1) * 64);
            }
        }
        #pragma unroll
        for (int ks = 0; ks < 2; ++ks) {
            bf16x8 af[4], bf[4];
            #pragma unroll
            for (int mb = 0; mb < 4; ++mb)
                af[mb] = *(const bf16x8*)(As + (size_t)(wm + mb * 16 + ln) * QKV_LDW
                                             + (ks * 4 + quad) * 8);
            #pragma unroll
            for (int nb = 0; nb < 4; ++nb)
                bf[nb] = *(const bf16x8*)(Bs + (size_t)(wn + nb * 16 + ln) * QKV_LDW
                                             + (ks * 4 + quad) * 8);
            if (mat != 2) {
                // swapped: acc[mb][nb][r] = C[m=mb*16+ln][n=nb*16+quad*4+r]
                #pragma unroll
                for (int mb = 0; mb < 4; ++mb)
                    #pragma unroll
                    for (int nb = 0; nb < 4; ++nb)
                        acc[mb][nb] = __builtin_amdgcn_mfma_f32_16x16x32_bf16(
                            bf[nb], af[mb], acc[mb][nb], 0, 0, 0);
            } else {
                // unswapped: acc[mb][nb][r] = C[m=mb*16+quad*4+r][n=nb*16+ln]
                #pragma unroll
                for (int mb = 0; mb < 4; ++mb)
                    #pragma unroll
                    for (int nb = 0; nb < 4; ++nb)
                        acc[mb][nb] = __builtin_amdgcn_mfma_f32_16x16x32_bf16(
                            af[mb], bf[nb], acc[mb][nb], 0, 0, 0);
            }
        }
    }

    if (mat != 2) {
        u16* outp = (mat == 0) ? q_out : k_out;
        const int h = n0 >> 7;   // one head per n-tile
        float4 bv[4];
        #pragma unroll
        for (int nb = 0; nb < 4; ++nb)
            bv[nb] = *(const float4*)&wb[n0 + wn + nb * 16 + quad * 4];
        #pragma unroll
        for (int mb = 0; mb < 4; ++mb) {
            const int m = m0 + wm + mb * 16 + ln;
            const int b = m >> 10, tok = m & 1023;
            u16* orow = outp + ((size_t)(b * NH + h) * SEQ + tok) * HD;
            #pragma unroll
            for (int nb = 0; nb < 4; ++nb) {
                const int d0 = wn + nb * 16 + quad * 4;
                ushort4 o;
                o.x = f2bf((acc[mb][nb][0] + bv[nb].x) * scale);
                o.y = f2bf((acc[mb][nb][1] + bv[nb].y) * scale);
                o.z = f2bf((acc[mb][nb][2] + bv[nb].z) * scale);
                o.w = f2bf((acc[mb][nb][3] + bv[nb].w) * scale);
                *(ushort4*)&orow[d0] = o;
            }
        }
    } else {
        // V: fused transpose -> Vt [bh][d][n]; 4 consecutive tokens per store
        #pragma unroll
        for (int nb = 0; nb < 4; ++nb) {
            const int c = n0 + wn + nb * 16 + ln;
            const float bv = wb[c];
            const int h = c >> 7, d = c & 127;
            #pragma unroll
            for (int mb = 0; mb < 4; ++mb) {
                const int m = m0 + wm + mb * 16 + quad * 4;
                const int b = m >> 10, tok0 = m & 1023;
                ushort4 o;
                o.x = f2bf(acc[mb][nb][0] + bv);
                o.y = f2bf(acc[mb][nb][1] + bv);
                o.z = f2bf(acc[mb][nb][2] + bv);
                o.w = f2bf(acc[mb][nb][3] + bv);
                *(ushort4*)&vt_out[((size_t)(b * NH + h) * HD + d) * SEQ + tok0] = o;
            }
        }
    }
}

// ---------------------------------------------------------------------------
// K2: flash attention, MFMA. R23: R20 structure with KVB 32 -> 64.
// grid (64 bh, 8 q-blocks), block 256, launch_bounds(256,2); wave owns 32
// q-rows (2 q-tiles) sharing one set of K/V fragment reads (R20 win).
// Rationale: attn pinned at ~57.5 us with no pipe >44% at 2 waves/SIMD
// (grid-limited: 512 blocks = 2 blocks/CU). At fixed occupancy the lever is
// per-wave stall: KVB=64 halves barrier count (32 -> 16 iters) and doubles
// per-phase ILP (16 QK + 16 PV MFMAs per phase). Total LDS instrs and
// fragment reads unchanged; key order identical -> bit-exact (two R20
// iterations concatenated). LDS 35.8 KB x 2 blocks = 71.6 <= 160 KB.
// Closed frontiers: R18 single-barrier dbuf (RACE); R19 K-direct-global
// (uncoalesced frag reads, 2.4x regress); R21 key-split 512-thr block
// (VGPR cap 128 -> accumulator spill, 2.2x regress). SQ_LDS_BANK_CONFLICT
// is structural 2-way accounting — not a lever.
// Unnormalized softmax (|s| <~ 10 << 88), p = exp(s), l in regs,
// in-register P via swapped QK^T + cvt_pk/permlane 4-quad transpose.
// Ks: [64 k][128 d] stride 136 u16; Vs: [128 d][64 k] stride 72 u16.
// Other negatives: XOR swizzle (R3/4), P pair-pack LDS (R7), V-direct (R9),
// bias-as-C (R13), exp2 fold (R14).
// ---------------------------------------------------------------------------
#define KVB    64
#define KS_LDW 136
#define VS_LDW 72
__global__ __launch_bounds__(256, 2) void attn_kernel(
    const u16* __restrict__ Q, const u16* __restrict__ K,
    const u16* __restrict__ Vt, const float* __restrict__ bias,
    u16* __restrict__ aout)
{
    __shared__ __align__(16) u16 Ks[KVB * KS_LDW];        // 17408 B
    __shared__ __align__(16) u16 Vs[128 * VS_LDW];        // 18432 B

    const int tid = threadIdx.x;
    const int lane = tid & 63, wave = tid >> 6;
    const int ln = lane & 15, quad = lane >> 4;
    const int bh = blockIdx.x;
    const int q0 = blockIdx.y * 128 + wave * 32;

    bf16x8 qf[2][4];
    #pragma unroll
    for (int mb = 0; mb < 2; ++mb) {
        const u16* qp = Q + ((size_t)bh * SEQ + q0 + mb * 16 + ln) * HD + quad * 8;
        #pragma unroll
        for (int ks = 0; ks < 4; ++ks) qf[mb][ks] = *(const bf16x8*)(qp + ks * 32);
    }

    f32x4 Oa[2][8];
    #pragma unroll
    for (int mb = 0; mb < 2; ++mb)
        #pragma unroll
        for (int db = 0; db < 8; ++db)
            #pragma unroll
            for (int r = 0; r < 4; ++r) Oa[mb][db][r] = 0.0f;
    float l_loc[2] = {0.0f, 0.0f};   // partial l for query ln, per q-tile

    const u16* Kg0 = K  + (size_t)bh * SEQ * HD;
    const u16* Vg0 = Vt + (size_t)bh * HD * SEQ;
    const float* brow0 = bias + (size_t)(q0 + ln) * SEQ + quad * 4;
    const float* brow1 = brow0 + (size_t)16 * SEQ;

    // staging indices
    const int r16 = tid >> 4, pb16 = tid & 15;   // K: 16 rows/pass, 4 passes
    const int r8  = tid >> 3, pb8  = tid & 7;    // V: 32 rows/pass, 4 passes

    const u16* kg = Kg0 + (size_t)r16 * HD + pb16 * 8;   // + kt*KVB*HD + c*16*HD
    const u16* vg = Vg0 + (size_t)r8 * SEQ + pb8 * 8;    // + c*32*SEQ + kt*KVB

    bf16x8 kp[4], vp[4];
    #pragma unroll
    for (int c = 0; c < 4; ++c) {
        kp[c] = *(const bf16x8*)(kg + (size_t)c * 16 * HD);
        vp[c] = *(const bf16x8*)(vg + (size_t)c * 32 * SEQ);
    }

    // bias prefetch for kt=0: [mb][nb] = keys nb*16 + quad*4 + {0..3}
    float4 bpre[2][4];
    #pragma unroll
    for (int mb = 0; mb < 2; ++mb)
        #pragma unroll
        for (int nb = 0; nb < 4; ++nb)
            bpre[mb][nb] = *(const float4*)((mb ? brow1 : brow0) + nb * 16);

    for (int kt = 0; kt < 16; ++kt) {
        __syncthreads();
        #pragma unroll
        for (int c = 0; c < 4; ++c) {
            *(bf16x8*)(Ks + (size_t)(c * 16 + r16) * KS_LDW + pb16 * 8) = kp[c];
            *(bf16x8*)(Vs + (size_t)(c * 32 + r8) * VS_LDW + pb8 * 8)   = vp[c];
        }
        __syncthreads();

        // prefetch next K/V tile (off critical path)
        if (kt < 15) {
            #pragma unroll
            for (int c = 0; c < 4; ++c) {
                kp[c] = *(const bf16x8*)(kg + (size_t)(kt + 1) * KVB * HD + (size_t)c * 16 * HD);
                vp[c] = *(const bf16x8*)(vg + (size_t)c * 32 * SEQ + (kt + 1) * KVB);
            }
        }

        // ---- S^T = K Q^T (swapped); kf shared by both q-tiles ----
        float p8[2][4][4];
        #pragma unroll
        for (int nb = 0; nb < 4; ++nb) {
            const u16* kr = Ks + (size_t)(nb * 16 + ln) * KS_LDW;
            bf16x8 kf[4];
            #pragma unroll
            for (int ks = 0; ks < 4; ++ks)
                kf[ks] = *(const bf16x8*)(kr + (ks * 4 + quad) * 8);
            #pragma unroll
            for (int mb = 0; mb < 2; ++mb) {
                f32x4 s;
                #pragma unroll
                for (int r = 0; r < 4; ++r) s[r] = 0.0f;
                #pragma unroll
                for (int ks = 0; ks < 4; ++ks)
                    s = __builtin_amdgcn_mfma_f32_16x16x32_bf16(kf[ks], qf[mb][ks], s, 0, 0, 0);
                #pragma unroll
                for (int r = 0; r < 4; ++r) {
                    const float p = __expf(s[r] + bpre[mb][nb][r]);
                    l_loc[mb] += p;
                    p8[mb][nb][r] = p;
                }
            }
        }

        // bias for kt+1 (after last use of bpre; hidden under PV)
        if (kt < 15) {
            #pragma unroll
            for (int mb = 0; mb < 2; ++mb)
                #pragma unroll
                for (int nb = 0; nb < 4; ++nb)
                    bpre[mb][nb] = *(const float4*)((mb ? brow1 : brow0)
                                                    + (kt + 1) * KVB + nb * 16);
        }

        // ---- P -> A fragments: pure-register 4-quad transpose ----
        // af[mb][h2] = P[q=ln][keys h2*32 + 8*quad .. +7]
        bf16x8 af[2][2];
        #pragma unroll
        for (int mb = 0; mb < 2; ++mb)
            #pragma unroll
            for (int h2 = 0; h2 < 2; ++h2) {
                unsigned x0 = cvt_pk_bf16(p8[mb][2 * h2][0], p8[mb][2 * h2][1]);
                unsigned x1 = cvt_pk_bf16(p8[mb][2 * h2][2], p8[mb][2 * h2][3]);
                unsigned y0 = cvt_pk_bf16(p8[mb][2 * h2 + 1][0], p8[mb][2 * h2 + 1][1]);
                unsigned y1 = cvt_pk_bf16(p8[mb][2 * h2 + 1][2], p8[mb][2 * h2 + 1][3]);
                asm("v_permlane32_swap_b32 %0, %1" : "+v"(x0), "+v"(y0));
                asm("v_permlane32_swap_b32 %0, %1" : "+v"(x1), "+v"(y1));
                asm("v_permlane16_swap_b32 %0, %1" : "+v"(x0), "+v"(y0));
                asm("v_permlane16_swap_b32 %0, %1" : "+v"(x1), "+v"(y1));
                union { unsigned u[4]; bf16x8 v; } afu;
                afu.u[0] = x0; afu.u[1] = x1; afu.u[2] = y0; afu.u[3] = y1;
                af[mb][h2] = afu.v;
            }

        // ---- O += P V; vf shared by both q-tiles; h2 in key order ----
        #pragma unroll
        for (int db = 0; db < 8; ++db) {
            #pragma unroll
            for (int h2 = 0; h2 < 2; ++h2) {
                bf16x8 vf = *(const bf16x8*)(Vs + (size_t)(db * 16 + ln) * VS_LDW
                                                + h2 * 32 + quad * 8);
                #pragma unroll
                for (int mb = 0; mb < 2; ++mb)
                    Oa[mb][db] = __builtin_amdgcn_mfma_f32_16x16x32_bf16(
                        af[mb][h2], vf, Oa[mb][db], 0, 0, 0);
            }
        }
    }

    // ---- l reduce across quads + epilogue, per q-tile ----
    const int b = bh >> 3, h = bh & 7;
    #pragma unroll
    for (int mb = 0; mb < 2; ++mb) {
        float ltot = l_loc[mb];
        ltot += __shfl_xor(ltot, 16);
        ltot += __shfl_xor(ltot, 32);
        #pragma unroll
        for (int r = 0; r < 4; ++r) {
            const float inv = 1.0f / __shfl(ltot, quad * 4 + r);
            const int tok = q0 + mb * 16 + quad * 4 + r;
            u16* op = aout + ((size_t)(b * SEQ + tok)) * CC + h * HD + ln;
            #pragma unroll
            for (int db = 0; db < 8; ++db) op[db * 16] = f2bf(Oa[mb][db][r] * inv);
        }
    }
}

// ---------------------------------------------------------------------------
// K3: output projection, 4-way K-split (R12-exact). M=8192, N=128, K=1024.
// grid 512, block 256 (4 waves). Wave kh owns K-quarter of the SAME 16 rows;
// waves 1-3 write fp32 partials to LDS (stride 132), wave 0 sums + bias.
// (2048 waves = 8 waves/CU; this was the R12 win, total 229 -> 197.)
// ---------------------------------------------------------------------------
__global__ __launch_bounds__(256) void proj_kernel(
    const u16* __restrict__ A, const u16* __restrict__ pT,
    const float* __restrict__ pb, float* __restrict__ out)
{
    __shared__ float Rs[3][16 * 132];
    const int tid = threadIdx.x;
    const int lane = tid & 63, kh = tid >> 6;
    const int ln = lane & 15, quad = lane >> 4;
    const int m0 = blockIdx.x * 16;

    f32x4 acc[8];
    #pragma unroll
    for (int nb = 0; nb < 8; ++nb)
        #pragma unroll
        for (int r = 0; r < 4; ++r) acc[nb][r] = 0.0f;

    const u16* ap = A  + (size_t)(m0 + ln) * CC + kh * 256 + quad * 8;
    const u16* bp = pT + (size_t)ln * CC + kh * 256 + quad * 8;

    #pragma unroll
    for (int kt = 0; kt < 8; ++kt) {
        bf16x8 af = *(const bf16x8*)(ap + kt * 32);
        #pragma unroll
        for (int nb = 0; nb < 8; ++nb) {
            bf16x8 bf = *(const bf16x8*)(bp + (size_t)nb * 16 * CC + kt * 32);
            acc[nb] = __builtin_amdgcn_mfma_f32_16x16x32_bf16(af, bf, acc[nb], 0, 0, 0);
        }
    }

    if (kh > 0) {
        #pragma unroll
        for (int nb = 0; nb < 8; ++nb)
            #pragma unroll
            for (int r = 0; r < 4; ++r)
                Rs[kh - 1][(quad * 4 + r) * 132 + nb * 16 + ln] = acc[nb][r];
    }
    __syncthreads();
    if (kh == 0) {
        #pragma unroll
        for (int nb = 0; nb < 8; ++nb) {
            const int c = nb * 16 + ln;
            const float bv = pb[c];
            #pragma unroll
            for (int r = 0; r < 4; ++r) {
                const int ri = (quad * 4 + r) * 132 + c;
                out[(size_t)(m0 + quad * 4 + r) * HD + c] =
                    acc[nb][r] + Rs[0][ri] + Rs[1][ri] + Rs[2][ri] + bv;
            }
        }
    }
}

// ---------------------------------------------------------------------------
extern "C" void kernel_launch(void* const* d_in, const int* in_sizes, int n_in,
                              void* d_out, int out_size, void* d_ws, size_t ws_size,
                              hipStream_t stream)
{
    const float* x    = (const float*)d_in[0];
    const float* bias = (const float*)d_in[1];
    const float* wq   = (const float*)d_in[2];
    const float* wqb  = (const float*)d_in[3];
    const float* wk   = (const float*)d_in[4];
    const float* wkb  = (const float*)d_in[5];
    const float* wv   = (const float*)d_in[6];
    const float* wvb  = (const float*)d_in[7];
    const float* pw   = (const float*)d_in[8];
    const float* pb   = (const float*)d_in[9];
    float* out = (float*)d_out;

    u16* ws = (u16*)d_ws;
    size_t off = 0;
    u16* xb  = ws + off; off += (size_t)8192 * IND;     // 4 MB
    u16* wqT = ws + off; off += (size_t)CC * IND;       // 512 KB
    u16* wkT = ws + off; off += (size_t)CC * IND;
    u16* wvT = ws + off; off += (size_t)CC * IND;
    u16* pT  = ws + off; off += (size_t)HD * CC;        // 256 KB
    u16* Qw  = ws + off; off += (size_t)BH * SEQ * HD;  // 16 MB
    u16* Kw  = ws + off; off += (size_t)BH * SEQ * HD;
    u16* Vtw = ws + off; off += (size_t)BH * HD * SEQ;
    u16* Aw  = ws + off; off += (size_t)8192 * CC;      // 16 MB

    prep_kernel<<<2944, 256, 0, stream>>>(x, xb, wq, wk, wv, wqT, wkT, wvT, pw, pT);
    qkv_kernel<<<dim3(64, 8, 3), 256, 0, stream>>>(
        xb, wqT, wkT, wvT, wqb, wkb, wvb, Qw, Kw, Vtw);
    attn_kernel<<<dim3(64, 8), 256, 0, stream>>>(Qw, Kw, Vtw, bias, Aw);
    proj_kernel<<<512, 256, 0, stream>>>(Aw, pT, pb, out);
}

// Round 10
// 177.951 us; speedup vs baseline: 1.3814x; 1.0074x over previous
//
#include <hip/hip_runtime.h>
#include <math.h>

#define SEQ  1024
#define IND  256
#define CC   1024
#define NH   8
#define HD   128
#define BH   64      // BATCH*NH

typedef __bf16 bf16x8 __attribute__((ext_vector_type(8)));
typedef __bf16 bf16x4 __attribute__((ext_vector_type(4)));
typedef float  f32x4  __attribute__((ext_vector_type(4)));
typedef unsigned short u16;

static constexpr float RSDK = 0.08838834764831845f;  // 1/sqrt(128)

__device__ __forceinline__ u16 f2bf(float f) {
    unsigned int u = __float_as_uint(f);
    u += 0x7fffu + ((u >> 16) & 1u);   // round-to-nearest-even
    return (u16)(u >> 16);
}

__device__ __forceinline__ unsigned cvt_pk_bf16(float lo, float hi) {
    unsigned r;
    asm("v_cvt_pk_bf16_f32 %0, %1, %2" : "=v"(r) : "v"(lo), "v"(hi));
    return r;
}

// ---------------------------------------------------------------------------
// P0: fused prep. 1D grid 2944, block 256.
//   id <  2048          : x fp32 -> bf16 (4 elems/thread)
//   2048 <= id < 2816   : wq/wk/wv [256][1024] -> bf16 [1024][256] transpose
//   2816 <= id < 2944   : proj_w [1024][128]  -> bf16 [128][1024] transpose
// ---------------------------------------------------------------------------
__global__ __launch_bounds__(256) void prep_kernel(
    const float* __restrict__ x, u16* __restrict__ xb,
    const float* __restrict__ w0, const float* __restrict__ w1, const float* __restrict__ w2,
    u16* __restrict__ o0, u16* __restrict__ o1, u16* __restrict__ o2,
    const float* __restrict__ pw, u16* __restrict__ pT)
{
    __shared__ float tile[32][33];
    const int id = blockIdx.x;

    if (id < 2048) {
        const int i = id * 256 + threadIdx.x;
        float4 v = ((const float4*)x)[i];
        ushort4 o;
        o.x = f2bf(v.x); o.y = f2bf(v.y); o.z = f2bf(v.z); o.w = f2bf(v.w);
        ((ushort4*)xb)[i] = o;
        return;
    }

    const float* in; u16* out; int R, C, c0, r0;
    if (id < 2816) {
        const int rem = id - 2048;
        const int z = rem >> 8;              // 0..2
        const int rem2 = rem & 255;
        in  = (z == 0) ? w0 : (z == 1) ? w1 : w2;
        out = (z == 0) ? o0 : (z == 1) ? o1 : o2;
        R = IND; C = CC;
        c0 = (rem2 & 31) * 32;               // 0..992
        r0 = (rem2 >> 5) * 32;               // 0..224
    } else {
        const int rem = id - 2816;
        in = pw; out = pT;
        R = CC; C = HD;
        c0 = (rem & 3) * 32;                 // 0..96
        r0 = (rem >> 2) * 32;                // 0..992
    }

    const int row = threadIdx.x >> 3, col4 = (threadIdx.x & 7) * 4;
    float4 v = *(const float4*)&in[(size_t)(r0 + row) * C + c0 + col4];
    tile[row][col4 + 0] = v.x; tile[row][col4 + 1] = v.y;
    tile[row][col4 + 2] = v.z; tile[row][col4 + 3] = v.w;
    __syncthreads();
    ushort4 o;
    o.x = f2bf(tile[col4 + 0][row]);
    o.y = f2bf(tile[col4 + 1][row]);
    o.z = f2bf(tile[col4 + 2][row]);
    o.w = f2bf(tile[col4 + 3][row]);
    *(ushort4*)&out[(size_t)(c0 + row) * R + r0 + col4] = o;
}

// ---------------------------------------------------------------------------
// K1: QKV MFMA GEMM — R23 hybrid (kept). M=8192,N=1024,K=256. grid (64,8,3),
// block 256. 128x128 tile, BK=64, PADDED rows (stride 72 u16) reg-staged
// (R12-proven; R22's gload_lds+linear-LDS was a wash). Q/K use SWAPPED
// operands mfma(bf, af) -> lane holds 4 consecutive d -> epilogue is 16
// ushort4 stores/lane (bit-exact; confirmed R22/R23). V unswapped +
// transposed ushort4 path. h = blockIdx.y.
// ---------------------------------------------------------------------------
#define QKV_LDW 72
__global__ __launch_bounds__(256) void qkv_kernel(
    const u16* __restrict__ xb,
    const u16* __restrict__ wT0, const u16* __restrict__ wT1, const u16* __restrict__ wT2,
    const float* __restrict__ b0, const float* __restrict__ b1, const float* __restrict__ b2,
    u16* __restrict__ q_out, u16* __restrict__ k_out, u16* __restrict__ vt_out)
{
    const int mat = blockIdx.z;
    const u16* wT  = (mat == 0) ? wT0 : (mat == 1) ? wT1 : wT2;
    const float* wb = (mat == 0) ? b0 : (mat == 1) ? b1 : b2;
    const float scale = (mat == 0) ? RSDK : 1.0f;

    __shared__ __align__(16) u16 As[128 * QKV_LDW];
    __shared__ __align__(16) u16 Bs[128 * QKV_LDW];

    const int tid = threadIdx.x;
    const int lane = tid & 63, wave = tid >> 6;
    const int ln = lane & 15, quad = lane >> 4;
    const int m0 = blockIdx.x * 128;
    const int n0 = blockIdx.y * 128;
    const int wm = (wave & 1) * 64;
    const int wn = (wave >> 1) * 64;

    f32x4 acc[4][4];
    #pragma unroll
    for (int mb = 0; mb < 4; ++mb)
        #pragma unroll
        for (int nb = 0; nb < 4; ++nb)
            #pragma unroll
            for (int r = 0; r < 4; ++r) acc[mb][nb][r] = 0.0f;

    const int r8 = tid >> 3, pb8 = tid & 7;   // row-within-32, 16B block

    const u16* ag = xb + (size_t)(m0 + r8) * IND + pb8 * 8;
    const u16* bg = wT + (size_t)(n0 + r8) * IND + pb8 * 8;

    bf16x8 pa[4], pbv[4];
    #pragma unroll
    for (int c = 0; c < 4; ++c) {
        pa[c]  = *(const bf16x8*)(ag + (size_t)c * 32 * IND);
        pbv[c] = *(const bf16x8*)(bg + (size_t)c * 32 * IND);
    }

    for (int kt = 0; kt < 4; ++kt) {
        __syncthreads();
        #pragma unroll
        for (int c = 0; c < 4; ++c) {
            *(bf16x8*)(As + (size_t)(c * 32 + r8) * QKV_LDW + pb8 * 8) = pa[c];
            *(bf16x8*)(Bs + (size_t)(c * 32 + r8) * QKV_LDW + pb8 * 8) = pbv[c];
        }
        __syncthreads();
        if (kt < 3) {
            #pragma unroll
            for (int c = 0; c < 4; ++c) {
                pa[c]  = *(const bf16x8*)(ag + (size_t)c * 32 * IND + (kt + 1) * 64);
                pbv[c] = *(const bf16x8*)(bg + (size_t)c * 32 * IND + (kt + 1) * 64);
            }
        }
        #pragma unroll
        for (int ks = 0; ks < 2; ++ks) {
            bf16x8 af[4], bf[4];
            #pragma unroll
            for (int mb = 0; mb < 4; ++mb)
                af[mb] = *(const bf16x8*)(As + (size_t)(wm + mb * 16 + ln) * QKV_LDW
                                             + (ks * 4 + quad) * 8);
            #pragma unroll
            for (int nb = 0; nb < 4; ++nb)
                bf[nb] = *(const bf16x8*)(Bs + (size_t)(wn + nb * 16 + ln) * QKV_LDW
                                             + (ks * 4 + quad) * 8);
            if (mat != 2) {
                // swapped: acc[mb][nb][r] = C[m=mb*16+ln][n=nb*16+quad*4+r]
                #pragma unroll
                for (int mb = 0; mb < 4; ++mb)
                    #pragma unroll
                    for (int nb = 0; nb < 4; ++nb)
                        acc[mb][nb] = __builtin_amdgcn_mfma_f32_16x16x32_bf16(
                            bf[nb], af[mb], acc[mb][nb], 0, 0, 0);
            } else {
                // unswapped: acc[mb][nb][r] = C[m=mb*16+quad*4+r][n=nb*16+ln]
                #pragma unroll
                for (int mb = 0; mb < 4; ++mb)
                    #pragma unroll
                    for (int nb = 0; nb < 4; ++nb)
                        acc[mb][nb] = __builtin_amdgcn_mfma_f32_16x16x32_bf16(
                            af[mb], bf[nb], acc[mb][nb], 0, 0, 0);
            }
        }
    }

    if (mat != 2) {
        u16* outp = (mat == 0) ? q_out : k_out;
        const int h = n0 >> 7;   // one head per n-tile
        float4 bv[4];
        #pragma unroll
        for (int nb = 0; nb < 4; ++nb)
            bv[nb] = *(const float4*)&wb[n0 + wn + nb * 16 + quad * 4];
        #pragma unroll
        for (int mb = 0; mb < 4; ++mb) {
            const int m = m0 + wm + mb * 16 + ln;
            const int b = m >> 10, tok = m & 1023;
            u16* orow = outp + ((size_t)(b * NH + h) * SEQ + tok) * HD;
            #pragma unroll
            for (int nb = 0; nb < 4; ++nb) {
                const int d0 = wn + nb * 16 + quad * 4;
                ushort4 o;
                o.x = f2bf((acc[mb][nb][0] + bv[nb].x) * scale);
                o.y = f2bf((acc[mb][nb][1] + bv[nb].y) * scale);
                o.z = f2bf((acc[mb][nb][2] + bv[nb].z) * scale);
                o.w = f2bf((acc[mb][nb][3] + bv[nb].w) * scale);
                *(ushort4*)&orow[d0] = o;
            }
        }
    } else {
        // V: fused transpose -> Vt [bh][d][n]; 4 consecutive tokens per store
        #pragma unroll
        for (int nb = 0; nb < 4; ++nb) {
            const int c = n0 + wn + nb * 16 + ln;
            const float bv = wb[c];
            const int h = c >> 7, d = c & 127;
            #pragma unroll
            for (int mb = 0; mb < 4; ++mb) {
                const int m = m0 + wm + mb * 16 + quad * 4;
                const int b = m >> 10, tok0 = m & 1023;
                ushort4 o;
                o.x = f2bf(acc[mb][nb][0] + bv);
                o.y = f2bf(acc[mb][nb][1] + bv);
                o.z = f2bf(acc[mb][nb][2] + bv);
                o.w = f2bf(acc[mb][nb][3] + bv);
                *(ushort4*)&vt_out[((size_t)(b * NH + h) * HD + d) * SEQ + tok0] = o;
            }
        }
    }
}

// ---------------------------------------------------------------------------
// K2: flash attention, MFMA. R20-EXACT restored (best measured: 57.5 us).
// Wave owns 32 q-rows (2 q-tiles) sharing one set of K/V fragment reads.
// grid (64 bh, 8 q-blocks), block 256, launch_bounds(256,2), KVB=32.
// Closed frontiers (do not revisit): R18 single-barrier dbuf (RACE);
// R19 K-direct-global (uncoalesced frag reads, 2.4x); R21 key-split 512-thr
// (VGPR cap -> spill, 2.2x); R23 KVB=64 (57.5 -> 62.5: doubled per-phase
// working set lengthened the serial VALU/transpose chain more than halved
// barriers saved — KVB=32 is the optimum). SQ_LDS_BANK_CONFLICT is
// structural 2-way accounting — not a lever.
// Unnormalized softmax (|s| <~ 10 << 88), p = exp(s), l in regs,
// in-register P via swapped QK^T + cvt_pk/permlane 4-quad transpose.
// Ks: [32 k][128 d] stride 136 u16; Vs: [128 d][32 k] stride 40 u16.
// Other negatives: XOR swizzle (R3/4), P pair-pack LDS (R7), V-direct (R9),
// bias-as-C (R13), exp2 fold (R14).
// ---------------------------------------------------------------------------
#define KVB    32
#define KS_LDW 136
#define VS_LDW 40
__global__ __launch_bounds__(256, 2) void attn_kernel(
    const u16* __restrict__ Q, const u16* __restrict__ K,
    const u16* __restrict__ Vt, const float* __restrict__ bias,
    u16* __restrict__ aout)
{
    __shared__ __align__(16) u16 Ks[KVB * KS_LDW];        // 8704 B
    __shared__ __align__(16) u16 Vs[128 * VS_LDW];        // 10240 B

    const int tid = threadIdx.x;
    const int lane = tid & 63, wave = tid >> 6;
    const int ln = lane & 15, quad = lane >> 4;
    const int bh = blockIdx.x;
    const int q0 = blockIdx.y * 128 + wave * 32;

    bf16x8 qf[2][4];
    #pragma unroll
    for (int mb = 0; mb < 2; ++mb) {
        const u16* qp = Q + ((size_t)bh * SEQ + q0 + mb * 16 + ln) * HD + quad * 8;
        #pragma unroll
        for (int ks = 0; ks < 4; ++ks) qf[mb][ks] = *(const bf16x8*)(qp + ks * 32);
    }

    f32x4 Oa[2][8];
    #pragma unroll
    for (int mb = 0; mb < 2; ++mb)
        #pragma unroll
        for (int db = 0; db < 8; ++db)
            #pragma unroll
            for (int r = 0; r < 4; ++r) Oa[mb][db][r] = 0.0f;
    float l_loc[2] = {0.0f, 0.0f};   // partial l for query ln, per q-tile

    const u16* Kg0 = K  + (size_t)bh * SEQ * HD;
    const u16* Vg0 = Vt + (size_t)bh * HD * SEQ;
    // bias rows for THIS lane's queries (ln per tile); float4 in key dim
    const float* brow0 = bias + (size_t)(q0 + ln) * SEQ + quad * 4;
    const float* brow1 = brow0 + (size_t)16 * SEQ;

    // staging indices (R17-exact)
    const int r16 = tid >> 4, pb16 = tid & 15;   // K: 16 rows/pass
    const int r4  = tid >> 2, pb4  = tid & 3;    // V: 64 rows/pass

    const u16* kg = Kg0 + (size_t)r16 * HD + pb16 * 8;   // + kt*KVB*HD + c*16*HD
    const u16* vg = Vg0 + (size_t)r4 * SEQ + pb4 * 8;    // + c*64*SEQ + kt*KVB

    bf16x8 kp[2], vp[2];
    #pragma unroll
    for (int c = 0; c < 2; ++c) {
        kp[c] = *(const bf16x8*)(kg + (size_t)c * 16 * HD);
        vp[c] = *(const bf16x8*)(vg + (size_t)c * 64 * SEQ);
    }

    // bias prefetch for kt=0: [mb][nb] = keys nb*16 + quad*4 + {0..3}
    float4 bpre[2][2];
    #pragma unroll
    for (int mb = 0; mb < 2; ++mb)
        #pragma unroll
        for (int nb = 0; nb < 2; ++nb)
            bpre[mb][nb] = *(const float4*)((mb ? brow1 : brow0) + nb * 16);

    for (int kt = 0; kt < 32; ++kt) {
        __syncthreads();
        #pragma unroll
        for (int c = 0; c < 2; ++c) {
            *(bf16x8*)(Ks + (size_t)(c * 16 + r16) * KS_LDW + pb16 * 8) = kp[c];
            *(bf16x8*)(Vs + (size_t)(c * 64 + r4) * VS_LDW + pb4 * 8)   = vp[c];
        }
        __syncthreads();

        // prefetch next K/V tile (off critical path)
        if (kt < 31) {
            #pragma unroll
            for (int c = 0; c < 2; ++c) {
                kp[c] = *(const bf16x8*)(kg + (size_t)(kt + 1) * KVB * HD + (size_t)c * 16 * HD);
                vp[c] = *(const bf16x8*)(vg + (size_t)c * 64 * SEQ + (kt + 1) * KVB);
            }
        }

        // ---- S^T = K Q^T (swapped); kf shared by both q-tiles ----
        float p8[2][2][4];
        #pragma unroll
        for (int nb = 0; nb < 2; ++nb) {
            const u16* kr = Ks + (size_t)(nb * 16 + ln) * KS_LDW;
            bf16x8 kf[4];
            #pragma unroll
            for (int ks = 0; ks < 4; ++ks)
                kf[ks] = *(const bf16x8*)(kr + (ks * 4 + quad) * 8);
            #pragma unroll
            for (int mb = 0; mb < 2; ++mb) {
                f32x4 s;
                #pragma unroll
                for (int r = 0; r < 4; ++r) s[r] = 0.0f;
                #pragma unroll
                for (int ks = 0; ks < 4; ++ks)
                    s = __builtin_amdgcn_mfma_f32_16x16x32_bf16(kf[ks], qf[mb][ks], s, 0, 0, 0);
                #pragma unroll
                for (int r = 0; r < 4; ++r) {
                    const float p = __expf(s[r] + bpre[mb][nb][r]);
                    l_loc[mb] += p;
                    p8[mb][nb][r] = p;
                }
            }
        }

        // bias for kt+1 (after last use of bpre; hidden under PV)
        if (kt < 31) {
            #pragma unroll
            for (int mb = 0; mb < 2; ++mb)
                #pragma unroll
                for (int nb = 0; nb < 2; ++nb)
                    bpre[mb][nb] = *(const float4*)((mb ? brow1 : brow0)
                                                    + (kt + 1) * KVB + nb * 16);
        }

        // ---- P -> A fragments: pure-register 4-quad transpose, per tile ----
        bf16x8 af[2];
        #pragma unroll
        for (int mb = 0; mb < 2; ++mb) {
            unsigned x0 = cvt_pk_bf16(p8[mb][0][0], p8[mb][0][1]);
            unsigned x1 = cvt_pk_bf16(p8[mb][0][2], p8[mb][0][3]);
            unsigned y0 = cvt_pk_bf16(p8[mb][1][0], p8[mb][1][1]);
            unsigned y1 = cvt_pk_bf16(p8[mb][1][2], p8[mb][1][3]);
            asm("v_permlane32_swap_b32 %0, %1" : "+v"(x0), "+v"(y0));
            asm("v_permlane32_swap_b32 %0, %1" : "+v"(x1), "+v"(y1));
            asm("v_permlane16_swap_b32 %0, %1" : "+v"(x0), "+v"(y0));
            asm("v_permlane16_swap_b32 %0, %1" : "+v"(x1), "+v"(y1));
            union { unsigned u[4]; bf16x8 v; } afu;
            afu.u[0] = x0; afu.u[1] = x1; afu.u[2] = y0; afu.u[3] = y1;
            af[mb] = afu.v;   // P[q=ln][keys 8*quad .. 8*quad+7]
        }

        // ---- O += P V; vf shared by both q-tiles ----
        #pragma unroll
        for (int db = 0; db < 8; ++db) {
            bf16x8 vf = *(const bf16x8*)(Vs + (size_t)(db * 16 + ln) * VS_LDW + quad * 8);
            #pragma unroll
            for (int mb = 0; mb < 2; ++mb)
                Oa[mb][db] = __builtin_amdgcn_mfma_f32_16x16x32_bf16(
                    af[mb], vf, Oa[mb][db], 0, 0, 0);
        }
    }

    // ---- l reduce across quads + epilogue, per q-tile ----
    const int b = bh >> 3, h = bh & 7;
    #pragma unroll
    for (int mb = 0; mb < 2; ++mb) {
        float ltot = l_loc[mb];
        ltot += __shfl_xor(ltot, 16);
        ltot += __shfl_xor(ltot, 32);
        #pragma unroll
        for (int r = 0; r < 4; ++r) {
            const float inv = 1.0f / __shfl(ltot, quad * 4 + r);
            const int tok = q0 + mb * 16 + quad * 4 + r;
            u16* op = aout + ((size_t)(b * SEQ + tok)) * CC + h * HD + ln;
            #pragma unroll
            for (int db = 0; db < 8; ++db) op[db * 16] = f2bf(Oa[mb][db][r] * inv);
        }
    }
}

// ---------------------------------------------------------------------------
// K3: output projection, 4-way K-split. R24: COALESCED A via LDS staging.
// M=8192, N=128, K=1024. grid 512, block 256 (4 waves); wave kh owns the
// K-quarter of the SAME 16 rows; waves 1-3 write fp32 partials to LDS,
// wave 0 sums + bias (R12 structure, values/order bit-exact).
// Previous ap read A[(m0+ln)*CC+...]: 16 lanes stride 2KB -> every bf16x8
// load shattered into 16 transactions (same defect as R19). Now A[16][1024]
// is staged coalesced (8 passes x 256 thr x 16B, row-contiguous) into
// As16 stride 1032 (ln-stride 516 dwords = 4 banks mod 32 -> 2-way, free);
// fragment reads come from LDS. pT reads stay global (256 KB, L2-resident).
// LDS 33.0 + 25.3 = 58.4 KB; 2 blocks/CU unchanged.
// ---------------------------------------------------------------------------
#define PJ_LDW 1032
__global__ __launch_bounds__(256) void proj_kernel(
    const u16* __restrict__ A, const u16* __restrict__ pT,
    const float* __restrict__ pb, float* __restrict__ out)
{
    __shared__ __align__(16) u16 As16[16 * PJ_LDW];   // 33024 B
    __shared__ float Rs[3][16 * 132];                 // 25344 B
    const int tid = threadIdx.x;
    const int lane = tid & 63, kh = tid >> 6;
    const int ln = lane & 15, quad = lane >> 4;
    const int m0 = blockIdx.x * 16;

    // ---- stage A[16][1024] coalesced: pass p loads rows 2p..2p+1 ----
    {
        const int row = tid >> 7;            // 0..1
        const int col = (tid & 127) * 8;     // 0..1016
        #pragma unroll
        for (int p = 0; p < 8; ++p) {
            const int r = p * 2 + row;
            *(bf16x8*)&As16[(size_t)r * PJ_LDW + col] =
                *(const bf16x8*)&A[(size_t)(m0 + r) * CC + col];
        }
    }
    __syncthreads();

    f32x4 acc[8];
    #pragma unroll
    for (int nb = 0; nb < 8; ++nb)
        #pragma unroll
        for (int r = 0; r < 4; ++r) acc[nb][r] = 0.0f;

    const u16* ap = As16 + (size_t)ln * PJ_LDW + kh * 256 + quad * 8;
    const u16* bp = pT + (size_t)ln * CC + kh * 256 + quad * 8;

    #pragma unroll
    for (int kt = 0; kt < 8; ++kt) {
        bf16x8 af = *(const bf16x8*)(ap + kt * 32);
        #pragma unroll
        for (int nb = 0; nb < 8; ++nb) {
            bf16x8 bf = *(const bf16x8*)(bp + (size_t)nb * 16 * CC + kt * 32);
            acc[nb] = __builtin_amdgcn_mfma_f32_16x16x32_bf16(af, bf, acc[nb], 0, 0, 0);
        }
    }

    if (kh > 0) {
        #pragma unroll
        for (int nb = 0; nb < 8; ++nb)
            #pragma unroll
            for (int r = 0; r < 4; ++r)
                Rs[kh - 1][(quad * 4 + r) * 132 + nb * 16 + ln] = acc[nb][r];
    }
    __syncthreads();
    if (kh == 0) {
        #pragma unroll
        for (int nb = 0; nb < 8; ++nb) {
            const int c = nb * 16 + ln;
            const float bv = pb[c];
            #pragma unroll
            for (int r = 0; r < 4; ++r) {
                const int ri = (quad * 4 + r) * 132 + c;
                out[(size_t)(m0 + quad * 4 + r) * HD + c] =
                    acc[nb][r] + Rs[0][ri] + Rs[1][ri] + Rs[2][ri] + bv;
            }
        }
    }
}

// ---------------------------------------------------------------------------
extern "C" void kernel_launch(void* const* d_in, const int* in_sizes, int n_in,
                              void* d_out, int out_size, void* d_ws, size_t ws_size,
                              hipStream_t stream)
{
    const float* x    = (const float*)d_in[0];
    const float* bias = (const float*)d_in[1];
    const float* wq   = (const float*)d_in[2];
    const float* wqb  = (const float*)d_in[3];
    const float* wk   = (const float*)d_in[4];
    const float* wkb  = (const float*)d_in[5];
    const float* wv   = (const float*)d_in[6];
    const float* wvb  = (const float*)d_in[7];
    const float* pw   = (const float*)d_in[8];
    const float* pb   = (const float*)d_in[9];
    float* out = (float*)d_out;

    u16* ws = (u16*)d_ws;
    size_t off = 0;
    u16* xb  = ws + off; off += (size_t)8192 * IND;     // 4 MB
    u16* wqT = ws + off; off += (size_t)CC * IND;       // 512 KB
    u16* wkT = ws + off; off += (size_t)CC * IND;
    u16* wvT = ws + off; off += (size_t)CC * IND;
    u16* pT  = ws + off; off += (size_t)HD * CC;        // 256 KB
    u16* Qw  = ws + off; off += (size_t)BH * SEQ * HD;  // 16 MB
    u16* Kw  = ws + off; off += (size_t)BH * SEQ * HD;
    u16* Vtw = ws + off; off += (size_t)BH * HD * SEQ;
    u16* Aw  = ws + off; off += (size_t)8192 * CC;      // 16 MB

    prep_kernel<<<2944, 256, 0, stream>>>(x, xb, wq, wk, wv, wqT, wkT, wvT, pw, pT);
    qkv_kernel<<<dim3(64, 8, 3), 256, 0, stream>>>(
        xb, wqT, wkT, wvT, wqb, wkb, wvb, Qw, Kw, Vtw);
    attn_kernel<<<dim3(64, 8), 256, 0, stream>>>(Qw, Kw, Vtw, bias, Aw);
    proj_kernel<<<512, 256, 0, stream>>>(Aw, pT, pb, out);
}